// Round 5
// baseline (526.530 us; speedup 1.0000x reference)
//
#include <hip/hip_runtime.h>

#define NN 4096
#define HD 64
#define KNB 15
#define NE 32768
#define NM (NE + NN*KNB)   // 94208 edges total (with duplicates)
#define W64 (NN/64)        // 64 u64 words per bitmap row
#define RB 4               // output rows per block in final_kernel

typedef unsigned long long u64;
typedef unsigned int u32;

// order-preserving float->uint map
__device__ __forceinline__ u32 fmapu(float f) {
  int i = __float_as_int(f);
  return (u32)(i ^ ((i >> 31) | 0x80000000));
}

__device__ __forceinline__ float dot64(const float* __restrict__ a,
                                       const float* __restrict__ b) {
  const float4* a4 = (const float4*)a;
  const float4* b4 = (const float4*)b;
  float s = 0.f;
#pragma unroll
  for (int t = 0; t < 16; ++t) {
    float4 x = a4[t], y = b4[t];
    s = fmaf(x.x, y.x, s); s = fmaf(x.y, y.y, s);
    s = fmaf(x.z, y.z, s); s = fmaf(x.w, y.w, s);
  }
  return s;
}

__device__ __forceinline__ void edge_decode(int m, const int* __restrict__ ei,
                                            const int* __restrict__ knn_idx,
                                            int& s, int& d) {
  if (m < NE) { s = ei[m]; d = ei[NE + m]; }
  else { int mm = m - NE; s = mm / KNB; d = knn_idx[mm]; }
}

__global__ void zero_kernel(u32* __restrict__ p, int n) {
  int i = blockIdx.x * 256 + threadIdx.x;
  int stride = gridDim.x * 256;
  for (; i < n; i += stride) p[i] = 0u;
}

// ---------- KNN: block per node; radix binary-search for 15th-smallest ------
__global__ __launch_bounds__(256) void knn_kernel(const float* __restrict__ pts,
                                                  int* __restrict__ knn_idx) {
  __shared__ u32 s_wcnt[4];
  __shared__ int s_eq[256];
  __shared__ u32 s_cnt[2];   // [0]=strict-less slots, [1]=equal count
  int i = blockIdx.x;
  int tid = threadIdx.x;
  int lane = tid & 63, wv = tid >> 6;
  float px = pts[i*3+0], py = pts[i*3+1], pz = pts[i*3+2];
  // match np: (x*x + y*y) + z*z, no fma contraction
  float sqi = __fadd_rn(__fadd_rn(__fmul_rn(px,px), __fmul_rn(py,py)), __fmul_rn(pz,pz));
  u32 key[16];
#pragma unroll
  for (int s = 0; s < 16; ++s) {
    int j = s*256 + tid;
    float x = pts[j*3+0], y = pts[j*3+1], z = pts[j*3+2];
    float sqj = __fadd_rn(__fadd_rn(__fmul_rn(x,x), __fmul_rn(y,y)), __fmul_rn(z,z));
    // match BLAS fma chain: acc = x*xj; fma(y,..); fma(z,..)
    float dot = fmaf(pz, z, fmaf(py, y, __fmul_rn(px, x)));
    float d2 = __fadd_rn(__fsub_rn(sqi, __fmul_rn(2.0f, dot)), sqj);
    key[s] = (j == i) ? 0xFFFFFFFFu : fmapu(d2);
  }
  // binary search on bits: tau = 15th smallest key
  u32 prefix = 0u;
  for (int b = 31; b >= 0; --b) {
    u32 trial = prefix | (1u << b);
    u32 c = 0;
#pragma unroll
    for (int s = 0; s < 16; ++s) c += (key[s] < trial) ? 1u : 0u;
#pragma unroll
    for (int off = 32; off >= 1; off >>= 1) c += __shfl_xor((int)c, off, 64);
    if (lane == 0) s_wcnt[wv] = c;
    __syncthreads();
    u32 total = s_wcnt[0] + s_wcnt[1] + s_wcnt[2] + s_wcnt[3];
    if (total < KNB) prefix = trial;   // uniform across block
    __syncthreads();
  }
  u32 tau = prefix;
  if (tid == 0) { s_cnt[0] = 0u; s_cnt[1] = 0u; }
  __syncthreads();
#pragma unroll
  for (int s = 0; s < 16; ++s) {
    int j = s*256 + tid;
    if (key[s] < tau) {
      u32 p = atomicAdd(&s_cnt[0], 1u);
      knn_idx[i*KNB + p] = j;
    } else if (key[s] == tau) {
      u32 p = atomicAdd(&s_cnt[1], 1u);
      if (p < 256u) s_eq[p] = j;
    }
  }
  __syncthreads();
  if (tid == 0) {
    int cls = (int)s_cnt[0];
    int ceq = (int)s_cnt[1]; if (ceq > 256) ceq = 256;
    int need = KNB - cls;
    for (int r = 0; r < need; ++r) {      // smallest indices among ties
      int best = 1 << 30, bidx = 0;
      for (int t = 0; t < ceq; ++t) {
        int v = s_eq[t];
        if (v < best) { best = v; bidx = t; }
      }
      s_eq[bidx] = 1 << 30;
      knn_idx[i*KNB + cls + r] = best;
    }
  }
}

// ---------- mark unique edges in row bitmap ----------
__global__ void bitmap_kernel(const int* __restrict__ ei, const int* __restrict__ knn_idx,
                              u64* __restrict__ bR) {
  int m = blockIdx.x * 256 + threadIdx.x;
  if (m >= NM) return;
  int s, d; edge_decode(m, ei, knn_idx, s, d);
  atomicOr(&bR[(size_t)s*W64 + (d >> 6)], 1ull << (d & 63));
}

// ---------- out-degrees from bitmap ----------
__global__ void deg_kernel(const u64* __restrict__ bR, int* __restrict__ outdeg) {
  int i = blockIdx.x * 256 + threadIdx.x;
  if (i >= NN) return;
  int c = 0;
  for (int w = 0; w < W64; ++w) c += __popcll(bR[(size_t)i*W64 + w]);
  outdeg[i] = c;
}

// ---------- exclusive scan of 4096 ints, single block ----------
__global__ __launch_bounds__(1024) void scan_kernel(const int* __restrict__ deg,
                                                    int* __restrict__ ptr) {
  __shared__ int part[1024];
  int t = threadIdx.x;
  int base = t * 4;
  int a0 = deg[base], a1 = deg[base+1], a2 = deg[base+2], a3 = deg[base+3];
  part[t] = a0 + a1 + a2 + a3;
  __syncthreads();
  for (int off = 1; off < 1024; off <<= 1) {
    int v = 0;
    if (t >= off) v = part[t - off];
    __syncthreads();
    if (t >= off) part[t] += v;
    __syncthreads();
  }
  int excl = (t > 0) ? part[t-1] : 0;
  ptr[base]   = excl;
  ptr[base+1] = excl + a0;
  ptr[base+2] = excl + a0 + a1;
  ptr[base+3] = excl + a0 + a1 + a2;
  if (t == 1023) ptr[NN] = part[1023];
}

// ---------- CSR fill from bitmap: cols + owner row id ----------
__global__ void fill_kernel(const u64* __restrict__ bR, const int* __restrict__ row_ptr,
                            int* __restrict__ csr_col, int* __restrict__ csr_rowid) {
  int i = blockIdx.x * 256 + threadIdx.x;
  if (i >= NN) return;
  int off = row_ptr[i];
  for (int w = 0; w < W64; ++w) {
    u64 b = bR[(size_t)i*W64 + w];
    while (b) {
      int t = __builtin_ctzll(b); b &= b - 1;
      csr_col[off] = w*64 + t; csr_rowid[off] = i; ++off;
    }
  }
}

// ---------- per-node max_j W_theta(p_j - p_i) over unique out-neighbors -----
__global__ __launch_bounds__(256) void theta_max_kernel(const float* __restrict__ pts,
    const int* __restrict__ row_ptr, const int* __restrict__ csr_col,
    const float* __restrict__ Wt, const float* __restrict__ bt,
    float* __restrict__ maxf) {
  int lane = threadIdx.x & 63, wv = threadIdx.x >> 6;
  int i = blockIdx.x * 4 + wv;
  float w0 = Wt[lane*3+0], w1 = Wt[lane*3+1], w2 = Wt[lane*3+2], bb = bt[lane];
  float px = pts[i*3+0], py = pts[i*3+1], pz = pts[i*3+2];
  float m = -INFINITY;
  int rb = row_ptr[i], re = row_ptr[i+1];
  for (int e = rb; e < re; ++e) {
    int d = csr_col[e];
    float dx = __fsub_rn(pts[d*3+0], px);
    float dy = __fsub_rn(pts[d*3+1], py);
    float dz = __fsub_rn(pts[d*3+2], pz);
    float t = fmaf(dz, w2, fmaf(dy, w1, __fmul_rn(dx, w0)));
    m = fmaxf(m, __fadd_rn(t, bb));
  }
  maxf[(size_t)i*HD + lane] = m;
}

// ---------- dev = relu(W_phi maxf + b); q, k ----------
__global__ __launch_bounds__(256) void dev_qk_kernel(const float* __restrict__ maxf,
    const float* __restrict__ Wp, const float* __restrict__ bp,
    const float* __restrict__ Wq, const float* __restrict__ bq,
    const float* __restrict__ Wk, const float* __restrict__ bk,
    float* __restrict__ qv, float* __restrict__ kv) {
  __shared__ float mf[4][HD];
  __shared__ float dv[4][HD];
  int lane = threadIdx.x & 63, sub = threadIdx.x >> 6;
  int node = blockIdx.x * 4 + sub;
  mf[sub][lane] = maxf[(size_t)node*HD + lane];
  __syncthreads();
  float a = 0.f;
#pragma unroll
  for (int t = 0; t < HD; ++t) a = fmaf(Wp[lane*HD + t], mf[sub][t], a);
  float dvv = a + bp[lane];
  dv[sub][lane] = dvv > 0.f ? dvv : 0.f;
  __syncthreads();
  float aq = 0.f, ak = 0.f;
#pragma unroll
  for (int t = 0; t < HD; ++t) {
    float x = dv[sub][t];
    aq = fmaf(Wq[lane*HD + t], x, aq);
    ak = fmaf(Wk[lane*HD + t], x, ak);
  }
  qv[(size_t)node*HD + lane] = aq + bq[lane];
  kv[(size_t)node*HD + lane] = ak + bk[lane];
}

// ---------- denom[s] = sum over ALL M edges (incl. duplicates) ----------
__global__ void denom_kernel(const int* __restrict__ ei, const int* __restrict__ knn_idx,
                             const float* __restrict__ qv, const float* __restrict__ kv,
                             float* __restrict__ denom) {
  int m = blockIdx.x * 256 + threadIdx.x;
  if (m >= NM) return;
  int s, d; edge_decode(m, ei, knn_idx, s, d);
  float e = expf(dot64(qv + (size_t)d*HD, kv + (size_t)s*HD));
  atomicAdd(&denom[s], e);
}

// ---------- attn values, edge-parallel; pack (col, val) into uint2 ----------
__global__ void vals_kernel(const int* __restrict__ row_ptr,
    const int* __restrict__ csr_col, const int* __restrict__ csr_rowid,
    const float* __restrict__ qv, const float* __restrict__ kv,
    const float* __restrict__ denom, uint2* __restrict__ cv) {
  int e = blockIdx.x * 256 + threadIdx.x;
  if (e >= row_ptr[NN]) return;
  int i = csr_rowid[e], col = csr_col[e];
  float s = dot64(qv + (size_t)col*HD, kv + (size_t)i*HD);
  float val = expf(s) / denom[i];
  cv[e] = make_uint2((u32)col, __float_as_uint(val));
}

// ---------- A_s rows [i0, i0+RB): T = attn@A scatter, then gather-B ---------
// Phase A: Trow[l][r] += attn[i0+r, k] for l in out(k), k in out(i0+r)
// Phase B: A_s[i0+r, j] = sum_{l in out(j)} attn[j,l] * Trow[l][r]  (no atomics)
__global__ __launch_bounds__(512) void final_kernel(
    const int* __restrict__ row_ptr, const uint2* __restrict__ cv,
    float* __restrict__ out) {
  __shared__ float Trow[NN * RB];   // [l][r] packed: 64KB
  int tid = threadIdx.x;
  int i0 = blockIdx.x * RB;
  float4* T4 = (float4*)Trow;
  float4 z4 = make_float4(0.f, 0.f, 0.f, 0.f);
  for (int t = tid; t < NN; t += 512) T4[t] = z4;
  __syncthreads();
  int wave = tid >> 6, lane = tid & 63;
  // Phase A: 2 waves per output row r
  {
    int r = wave & (RB - 1);
    int i = i0 + r;
    int rb = row_ptr[i], re = row_ptr[i+1];
    for (int idx = rb + (wave >> 2); idx < re; idx += 2) {
      uint2 e = cv[idx];
      int k = (int)e.x;
      float wv = __uint_as_float(e.y);
      int kb = row_ptr[k], ke = row_ptr[k+1];
      for (int t = kb + lane; t < ke; t += 64)
        atomicAdd(&Trow[cv[t].x * RB + r], wv);
    }
  }
  __syncthreads();
  // Phase B: thread per output column j; register accumulate; direct store
  for (int j = tid; j < NN; j += 512) {
    int cb = row_ptr[j], ce = row_ptr[j+1];
    float s0 = 0.f, s1 = 0.f, s2 = 0.f, s3 = 0.f;
    for (int t = cb; t < ce; ++t) {
      uint2 e = cv[t];
      float av = __uint_as_float(e.y);
      float4 tv = T4[e.x];
      s0 = fmaf(av, tv.x, s0); s1 = fmaf(av, tv.y, s1);
      s2 = fmaf(av, tv.z, s2); s3 = fmaf(av, tv.w, s3);
    }
    out[(size_t)(i0+0)*NN + j] = s0;
    out[(size_t)(i0+1)*NN + j] = s1;
    out[(size_t)(i0+2)*NN + j] = s2;
    out[(size_t)(i0+3)*NN + j] = s3;
  }
}

extern "C" void kernel_launch(void* const* d_in, const int* in_sizes, int n_in,
                              void* d_out, int out_size, void* d_ws, size_t ws_size,
                              hipStream_t stream) {
  (void)in_sizes; (void)n_in; (void)out_size;
  const float* pts = (const float*)d_in[0];
  // d_in[1] = features: unused by the reference
  const int* ei = (const int*)d_in[2];
  const float* Wt = (const float*)d_in[3];
  const float* bt = (const float*)d_in[4];
  const float* Wp = (const float*)d_in[5];
  const float* bp = (const float*)d_in[6];
  const float* Wq = (const float*)d_in[7];
  const float* bq = (const float*)d_in[8];
  const float* Wk = (const float*)d_in[9];
  const float* bk = (const float*)d_in[10];
  float* out = (float*)d_out;

  char* w = (char*)d_ws;
  // zeroed region first (contiguous): bR, denom
  u64* bR = (u64*)w;        w += (size_t)NN*W64*8;   // 2MB
  float* denom = (float*)w; w += (size_t)NN*4;       // 16KB
  float* maxf = (float*)w;  w += (size_t)NN*HD*4;    // 1MB
  float* qv = (float*)w;    w += (size_t)NN*HD*4;    // 1MB
  float* kv = (float*)w;    w += (size_t)NN*HD*4;    // 1MB
  int* knn_idx = (int*)w;   w += (size_t)NN*KNB*4;
  int* outdeg = (int*)w;    w += (size_t)NN*4;
  int* row_ptr = (int*)w;   w += (size_t)(NN+4)*4;
  int* csr_col = (int*)w;   w += (size_t)NM*4;
  int* csr_rowid = (int*)w; w += (size_t)NM*4;
  uint2* cv = (uint2*)w;    w += (size_t)NM*8;
  if ((size_t)(w - (char*)d_ws) > ws_size) return;  // insufficient scratch

  int zero_u32s = (int)(((size_t)NN*W64*8 + (size_t)NN*4) / 4);
  hipLaunchKernelGGL(zero_kernel, dim3(2048), dim3(256), 0, stream, (u32*)d_ws, zero_u32s);
  hipLaunchKernelGGL(knn_kernel, dim3(NN), dim3(256), 0, stream, pts, knn_idx);
  hipLaunchKernelGGL(bitmap_kernel, dim3((NM+255)/256), dim3(256), 0, stream,
                     ei, knn_idx, bR);
  hipLaunchKernelGGL(deg_kernel, dim3(NN/256), dim3(256), 0, stream, bR, outdeg);
  hipLaunchKernelGGL(scan_kernel, dim3(1), dim3(1024), 0, stream, outdeg, row_ptr);
  hipLaunchKernelGGL(fill_kernel, dim3(NN/256), dim3(256), 0, stream,
                     bR, row_ptr, csr_col, csr_rowid);
  hipLaunchKernelGGL(theta_max_kernel, dim3(NN/4), dim3(256), 0, stream,
                     pts, row_ptr, csr_col, Wt, bt, maxf);
  hipLaunchKernelGGL(dev_qk_kernel, dim3(NN/4), dim3(256), 0, stream,
                     maxf, Wp, bp, Wq, bq, Wk, bk, qv, kv);
  hipLaunchKernelGGL(denom_kernel, dim3((NM+255)/256), dim3(256), 0, stream,
                     ei, knn_idx, qv, kv, denom);
  hipLaunchKernelGGL(vals_kernel, dim3((NM+255)/256), dim3(256), 0, stream,
                     row_ptr, csr_col, csr_rowid, qv, kv, denom, cv);
  hipLaunchKernelGGL(final_kernel, dim3(NN/RB), dim3(512), 0, stream,
                     row_ptr, cv, out);
}

// Round 6
// 276.905 us; speedup vs baseline: 1.9015x; 1.9015x over previous
//
#include <hip/hip_runtime.h>

#define NN 4096
#define HD 64
#define KNB 15
#define NE 32768
#define NM (NE + NN*KNB)   // 94208 edges total (with duplicates)
#define W64 (NN/64)        // 64 u64 words per bitmap row
#define RB 4               // output rows per block in final_kernel
#define MAXH 96            // max slices per 64-col chunk (max degree bound)
#define NCH (NN/64)        // 64 column chunks

typedef unsigned long long u64;
typedef unsigned int u32;

// order-preserving float->uint map
__device__ __forceinline__ u32 fmapu(float f) {
  int i = __float_as_int(f);
  return (u32)(i ^ ((i >> 31) | 0x80000000));
}

__device__ __forceinline__ float dot64(const float* __restrict__ a,
                                       const float* __restrict__ b) {
  const float4* a4 = (const float4*)a;
  const float4* b4 = (const float4*)b;
  float s = 0.f;
#pragma unroll
  for (int t = 0; t < 16; ++t) {
    float4 x = a4[t], y = b4[t];
    s = fmaf(x.x, y.x, s); s = fmaf(x.y, y.y, s);
    s = fmaf(x.z, y.z, s); s = fmaf(x.w, y.w, s);
  }
  return s;
}

__device__ __forceinline__ void edge_decode(int m, const int* __restrict__ ei,
                                            const int* __restrict__ knn_idx,
                                            int& s, int& d) {
  if (m < NE) { s = ei[m]; d = ei[NE + m]; }
  else { int mm = m - NE; s = mm / KNB; d = knn_idx[mm]; }
}

__global__ void zero_kernel(u32* __restrict__ p, int n) {
  int i = blockIdx.x * 256 + threadIdx.x;
  int stride = gridDim.x * 256;
  for (; i < n; i += stride) p[i] = 0u;
}

// ---------- KNN: block per node; radix binary-search for 15th-smallest ------
__global__ __launch_bounds__(256) void knn_kernel(const float* __restrict__ pts,
                                                  int* __restrict__ knn_idx) {
  __shared__ u32 s_wcnt[4];
  __shared__ int s_eq[256];
  __shared__ u32 s_cnt[2];   // [0]=strict-less slots, [1]=equal count
  int i = blockIdx.x;
  int tid = threadIdx.x;
  int lane = tid & 63, wv = tid >> 6;
  float px = pts[i*3+0], py = pts[i*3+1], pz = pts[i*3+2];
  // match np: (x*x + y*y) + z*z, no fma contraction
  float sqi = __fadd_rn(__fadd_rn(__fmul_rn(px,px), __fmul_rn(py,py)), __fmul_rn(pz,pz));
  u32 key[16];
#pragma unroll
  for (int s = 0; s < 16; ++s) {
    int j = s*256 + tid;
    float x = pts[j*3+0], y = pts[j*3+1], z = pts[j*3+2];
    float sqj = __fadd_rn(__fadd_rn(__fmul_rn(x,x), __fmul_rn(y,y)), __fmul_rn(z,z));
    // match BLAS fma chain: acc = x*xj; fma(y,..); fma(z,..)
    float dot = fmaf(pz, z, fmaf(py, y, __fmul_rn(px, x)));
    float d2 = __fadd_rn(__fsub_rn(sqi, __fmul_rn(2.0f, dot)), sqj);
    key[s] = (j == i) ? 0xFFFFFFFFu : fmapu(d2);
  }
  // binary search on bits: tau = 15th smallest key
  u32 prefix = 0u;
  for (int b = 31; b >= 0; --b) {
    u32 trial = prefix | (1u << b);
    u32 c = 0;
#pragma unroll
    for (int s = 0; s < 16; ++s) c += (key[s] < trial) ? 1u : 0u;
#pragma unroll
    for (int off = 32; off >= 1; off >>= 1) c += __shfl_xor((int)c, off, 64);
    if (lane == 0) s_wcnt[wv] = c;
    __syncthreads();
    u32 total = s_wcnt[0] + s_wcnt[1] + s_wcnt[2] + s_wcnt[3];
    if (total < KNB) prefix = trial;   // uniform across block
    __syncthreads();
  }
  u32 tau = prefix;
  if (tid == 0) { s_cnt[0] = 0u; s_cnt[1] = 0u; }
  __syncthreads();
#pragma unroll
  for (int s = 0; s < 16; ++s) {
    int j = s*256 + tid;
    if (key[s] < tau) {
      u32 p = atomicAdd(&s_cnt[0], 1u);
      knn_idx[i*KNB + p] = j;
    } else if (key[s] == tau) {
      u32 p = atomicAdd(&s_cnt[1], 1u);
      if (p < 256u) s_eq[p] = j;
    }
  }
  __syncthreads();
  if (tid == 0) {
    int cls = (int)s_cnt[0];
    int ceq = (int)s_cnt[1]; if (ceq > 256) ceq = 256;
    int need = KNB - cls;
    for (int r = 0; r < need; ++r) {      // smallest indices among ties
      int best = 1 << 30, bidx = 0;
      for (int t = 0; t < ceq; ++t) {
        int v = s_eq[t];
        if (v < best) { best = v; bidx = t; }
      }
      s_eq[bidx] = 1 << 30;
      knn_idx[i*KNB + cls + r] = best;
    }
  }
}

// ---------- mark unique edges in row bitmap ----------
__global__ void bitmap_kernel(const int* __restrict__ ei, const int* __restrict__ knn_idx,
                              u64* __restrict__ bR) {
  int m = blockIdx.x * 256 + threadIdx.x;
  if (m >= NM) return;
  int s, d; edge_decode(m, ei, knn_idx, s, d);
  atomicOr(&bR[(size_t)s*W64 + (d >> 6)], 1ull << (d & 63));
}

// ---------- out-degrees from bitmap ----------
__global__ void deg_kernel(const u64* __restrict__ bR, int* __restrict__ outdeg) {
  int i = blockIdx.x * 256 + threadIdx.x;
  if (i >= NN) return;
  int c = 0;
  for (int w = 0; w < W64; ++w) c += __popcll(bR[(size_t)i*W64 + w]);
  outdeg[i] = c;
}

// ---------- exclusive scan of 4096 ints, single block ----------
__global__ __launch_bounds__(1024) void scan_kernel(const int* __restrict__ deg,
                                                    int* __restrict__ ptr) {
  __shared__ int part[1024];
  int t = threadIdx.x;
  int base = t * 4;
  int a0 = deg[base], a1 = deg[base+1], a2 = deg[base+2], a3 = deg[base+3];
  part[t] = a0 + a1 + a2 + a3;
  __syncthreads();
  for (int off = 1; off < 1024; off <<= 1) {
    int v = 0;
    if (t >= off) v = part[t - off];
    __syncthreads();
    if (t >= off) part[t] += v;
    __syncthreads();
  }
  int excl = (t > 0) ? part[t-1] : 0;
  ptr[base]   = excl;
  ptr[base+1] = excl + a0;
  ptr[base+2] = excl + a0 + a1;
  ptr[base+3] = excl + a0 + a1 + a2;
  if (t == 1023) ptr[NN] = part[1023];
}

// ---------- CSR fill from bitmap: cols + owner row id ----------
__global__ void fill_kernel(const u64* __restrict__ bR, const int* __restrict__ row_ptr,
                            int* __restrict__ csr_col, int* __restrict__ csr_rowid) {
  int i = blockIdx.x * 256 + threadIdx.x;
  if (i >= NN) return;
  int off = row_ptr[i];
  for (int w = 0; w < W64; ++w) {
    u64 b = bR[(size_t)i*W64 + w];
    while (b) {
      int t = __builtin_ctzll(b); b &= b - 1;
      csr_col[off] = w*64 + t; csr_rowid[off] = i; ++off;
    }
  }
}

// ---------- sliced-ELL metadata: per-chunk max degree + slice offsets -------
__global__ __launch_bounds__(1024) void ell_meta_kernel(const int* __restrict__ row_ptr,
                                                        int* __restrict__ H,
                                                        int* __restrict__ off) {
  __shared__ int sH[NCH];
  int tid = threadIdx.x;
  if (tid < NCH) sH[tid] = 0;
  __syncthreads();
  for (int j = tid; j < NN; j += 1024) {
    int d = row_ptr[j+1] - row_ptr[j];
    atomicMax(&sH[j >> 6], d);
  }
  __syncthreads();
  if (tid < 64) {     // exactly wave 0
    int h = sH[tid]; if (h > MAXH) h = MAXH;
    H[tid] = h;
    int x = h;        // inclusive scan across 64 lanes
#pragma unroll
    for (int o = 1; o < 64; o <<= 1) {
      int v = __shfl_up(x, o, 64);
      if (tid >= o) x += v;
    }
    off[tid + 1] = x;
    if (tid == 0) off[0] = 0;
  }
}

// ---------- per-node max_j W_theta(p_j - p_i) over unique out-neighbors -----
__global__ __launch_bounds__(256) void theta_max_kernel(const float* __restrict__ pts,
    const int* __restrict__ row_ptr, const int* __restrict__ csr_col,
    const float* __restrict__ Wt, const float* __restrict__ bt,
    float* __restrict__ maxf) {
  int lane = threadIdx.x & 63, wv = threadIdx.x >> 6;
  int i = blockIdx.x * 4 + wv;
  float w0 = Wt[lane*3+0], w1 = Wt[lane*3+1], w2 = Wt[lane*3+2], bb = bt[lane];
  float px = pts[i*3+0], py = pts[i*3+1], pz = pts[i*3+2];
  float m = -INFINITY;
  int rb = row_ptr[i], re = row_ptr[i+1];
  for (int e = rb; e < re; ++e) {
    int d = csr_col[e];
    float dx = __fsub_rn(pts[d*3+0], px);
    float dy = __fsub_rn(pts[d*3+1], py);
    float dz = __fsub_rn(pts[d*3+2], pz);
    float t = fmaf(dz, w2, fmaf(dy, w1, __fmul_rn(dx, w0)));
    m = fmaxf(m, __fadd_rn(t, bb));
  }
  maxf[(size_t)i*HD + lane] = m;
}

// ---------- dev = relu(W_phi maxf + b); q, k ----------
__global__ __launch_bounds__(256) void dev_qk_kernel(const float* __restrict__ maxf,
    const float* __restrict__ Wp, const float* __restrict__ bp,
    const float* __restrict__ Wq, const float* __restrict__ bq,
    const float* __restrict__ Wk, const float* __restrict__ bk,
    float* __restrict__ qv, float* __restrict__ kv) {
  __shared__ float mf[4][HD];
  __shared__ float dv[4][HD];
  int lane = threadIdx.x & 63, sub = threadIdx.x >> 6;
  int node = blockIdx.x * 4 + sub;
  mf[sub][lane] = maxf[(size_t)node*HD + lane];
  __syncthreads();
  float a = 0.f;
#pragma unroll
  for (int t = 0; t < HD; ++t) a = fmaf(Wp[lane*HD + t], mf[sub][t], a);
  float dvv = a + bp[lane];
  dv[sub][lane] = dvv > 0.f ? dvv : 0.f;
  __syncthreads();
  float aq = 0.f, ak = 0.f;
#pragma unroll
  for (int t = 0; t < HD; ++t) {
    float x = dv[sub][t];
    aq = fmaf(Wq[lane*HD + t], x, aq);
    ak = fmaf(Wk[lane*HD + t], x, ak);
  }
  qv[(size_t)node*HD + lane] = aq + bq[lane];
  kv[(size_t)node*HD + lane] = ak + bk[lane];
}

// ---------- denom[s] = sum over ALL M edges (incl. duplicates) ----------
__global__ void denom_kernel(const int* __restrict__ ei, const int* __restrict__ knn_idx,
                             const float* __restrict__ qv, const float* __restrict__ kv,
                             float* __restrict__ denom) {
  int m = blockIdx.x * 256 + threadIdx.x;
  if (m >= NM) return;
  int s, d; edge_decode(m, ei, knn_idx, s, d);
  float e = expf(dot64(qv + (size_t)d*HD, kv + (size_t)s*HD));
  atomicAdd(&denom[s], e);
}

// ---------- attn values: write CSR stream (cv) + sliced-ELL (cvT) ----------
__global__ void vals_kernel(const int* __restrict__ row_ptr,
    const int* __restrict__ csr_col, const int* __restrict__ csr_rowid,
    const float* __restrict__ qv, const float* __restrict__ kv,
    const float* __restrict__ denom, const int* __restrict__ off,
    uint2* __restrict__ cv, uint2* __restrict__ cvT) {
  int e = blockIdx.x * 256 + threadIdx.x;
  if (e >= row_ptr[NN]) return;
  int i = csr_rowid[e], col = csr_col[e];
  float s = dot64(qv + (size_t)col*HD, kv + (size_t)i*HD);
  float val = expf(s) / denom[i];
  uint2 u = make_uint2((u32)col, __float_as_uint(val));
  cv[e] = u;
  int sidx = e - row_ptr[i];
  if (sidx < MAXH)
    cvT[(((size_t)off[i >> 6] + sidx) << 6) + (i & 63)] = u;
}

// ---------- A_s rows [i0,i0+4): Phase A scatter into LDS planes, -----------
// Phase B coalesced sliced-ELL gather with register accumulators (no atomics)
__global__ __launch_bounds__(1024, 8) void final_kernel(
    const int* __restrict__ row_ptr, const uint2* __restrict__ cv,
    const uint2* __restrict__ cvT, const int* __restrict__ H,
    const int* __restrict__ off, float* __restrict__ out) {
  __shared__ float T0[NN], T1[NN], T2[NN], T3[NN];   // 64KB: T[l][r] planes
  int tid = threadIdx.x;
  int i0 = blockIdx.x * RB;
  for (int t = tid; t < NN; t += 1024) { T0[t]=0.f; T1[t]=0.f; T2[t]=0.f; T3[t]=0.f; }
  __syncthreads();
  int w = tid >> 6, lane = tid & 63;
  // Phase A: 4 waves per output row r; Trow_r[l] += attn[i0+r,k] for l in out(k)
  {
    int r = w & (RB - 1);
    int i = i0 + r;
    float* Tr = (r == 0) ? T0 : ((r == 1) ? T1 : ((r == 2) ? T2 : T3));
    int rb = row_ptr[i], re = row_ptr[i+1];
    for (int idx = rb + (w >> 2); idx < re; idx += RB) {
      uint2 e = cv[idx];
      int k = (int)e.x; float wv = __uint_as_float(e.y);
      int kb = row_ptr[k], ke = row_ptr[k+1];
      for (int t = kb + lane; t < ke; t += 64)
        atomicAdd(&Tr[cv[t].x], wv);
    }
  }
  __syncthreads();
  // Phase B: thread owns cols {tid + g*1024}; wave reads coalesced ELL slices
  float acc[4][RB];
#pragma unroll
  for (int g = 0; g < 4; ++g)
#pragma unroll
    for (int r = 0; r < RB; ++r) acc[g][r] = 0.f;
#pragma unroll
  for (int g = 0; g < 4; ++g) {
    int j = tid + g * 1024;
    int c = j >> 6;                 // wave-uniform chunk
    int Hc = H[c];
    const uint2* p = cvT + (((size_t)off[c]) << 6) + (j & 63);
    for (int s = 0; s < Hc; ++s) {
      uint2 e = p[(size_t)s << 6];  // coalesced: lane-consecutive
      float v = __uint_as_float(e.y);
      int x = (int)e.x;
      acc[g][0] = fmaf(v, T0[x], acc[g][0]);
      acc[g][1] = fmaf(v, T1[x], acc[g][1]);
      acc[g][2] = fmaf(v, T2[x], acc[g][2]);
      acc[g][3] = fmaf(v, T3[x], acc[g][3]);
    }
  }
#pragma unroll
  for (int r = 0; r < RB; ++r) {
    size_t ro = (size_t)(i0 + r) * NN;
#pragma unroll
    for (int g = 0; g < 4; ++g) out[ro + tid + g * 1024] = acc[g][r];
  }
}

extern "C" void kernel_launch(void* const* d_in, const int* in_sizes, int n_in,
                              void* d_out, int out_size, void* d_ws, size_t ws_size,
                              hipStream_t stream) {
  (void)in_sizes; (void)n_in; (void)out_size;
  const float* pts = (const float*)d_in[0];
  // d_in[1] = features: unused by the reference
  const int* ei = (const int*)d_in[2];
  const float* Wt = (const float*)d_in[3];
  const float* bt = (const float*)d_in[4];
  const float* Wp = (const float*)d_in[5];
  const float* bp = (const float*)d_in[6];
  const float* Wq = (const float*)d_in[7];
  const float* bq = (const float*)d_in[8];
  const float* Wk = (const float*)d_in[9];
  const float* bk = (const float*)d_in[10];
  float* out = (float*)d_out;

  char* w = (char*)d_ws;
  // [bR 2MB][maxf 1MB] <- cvT (3MB) reuses this region after both are dead
  u64* bR = (u64*)w;        w += (size_t)NN*W64*8;       // 2MB
  float* maxf = (float*)w;  w += (size_t)NN*HD*4;        // 1MB
  uint2* cvT = (uint2*)d_ws;                             // 64*MAXH*64*8 = 3MB
  float* denom = (float*)w; w += (size_t)NN*4;           // 16KB
  float* qv = (float*)w;    w += (size_t)NN*HD*4;        // 1MB
  float* kv = (float*)w;    w += (size_t)NN*HD*4;        // 1MB
  int* knn_idx = (int*)w;   w += (size_t)NN*KNB*4;
  int* outdeg = (int*)w;    w += (size_t)NN*4;
  int* row_ptr = (int*)w;   w += (size_t)(NN+4)*4;
  int* Harr = (int*)w;      w += (size_t)NCH*4;
  int* off = (int*)w;       w += (size_t)(NCH+4)*4;
  int* csr_col = (int*)w;   w += (size_t)NM*4;
  int* csr_rowid = (int*)w; w += (size_t)NM*4;
  uint2* cv = (uint2*)w;    w += (size_t)NM*8;
  if ((size_t)(w - (char*)d_ws) > ws_size) return;  // insufficient scratch
  if ((size_t)NCH*MAXH*64*8 > (size_t)NN*W64*8 + (size_t)NN*HD*4) return; // cvT fits bR+maxf

  // zero bR + (maxf slack) + denom in one contiguous pass
  int zero1 = (int)(((size_t)NN*W64*8 + (size_t)NN*HD*4 + (size_t)NN*4) / 4);
  hipLaunchKernelGGL(zero_kernel, dim3(2048), dim3(256), 0, stream, (u32*)d_ws, zero1);
  hipLaunchKernelGGL(knn_kernel, dim3(NN), dim3(256), 0, stream, pts, knn_idx);
  hipLaunchKernelGGL(bitmap_kernel, dim3((NM+255)/256), dim3(256), 0, stream,
                     ei, knn_idx, bR);
  hipLaunchKernelGGL(deg_kernel, dim3(NN/256), dim3(256), 0, stream, bR, outdeg);
  hipLaunchKernelGGL(scan_kernel, dim3(1), dim3(1024), 0, stream, outdeg, row_ptr);
  hipLaunchKernelGGL(fill_kernel, dim3(NN/256), dim3(256), 0, stream,
                     bR, row_ptr, csr_col, csr_rowid);
  hipLaunchKernelGGL(ell_meta_kernel, dim3(1), dim3(1024), 0, stream,
                     row_ptr, Harr, off);
  hipLaunchKernelGGL(theta_max_kernel, dim3(NN/4), dim3(256), 0, stream,
                     pts, row_ptr, csr_col, Wt, bt, maxf);
  hipLaunchKernelGGL(dev_qk_kernel, dim3(NN/4), dim3(256), 0, stream,
                     maxf, Wp, bp, Wq, bq, Wk, bk, qv, kv);
  // bR and maxf are now dead: zero cvT region (3MB) for ELL padding
  int zero2 = (int)((size_t)NCH*MAXH*64*8 / 4);
  hipLaunchKernelGGL(zero_kernel, dim3(2048), dim3(256), 0, stream, (u32*)d_ws, zero2);
  hipLaunchKernelGGL(denom_kernel, dim3((NM+255)/256), dim3(256), 0, stream,
                     ei, knn_idx, qv, kv, denom);
  hipLaunchKernelGGL(vals_kernel, dim3((NM+255)/256), dim3(256), 0, stream,
                     row_ptr, csr_col, csr_rowid, qv, kv, denom, off, cv, cvT);
  hipLaunchKernelGGL(final_kernel, dim3(NN/RB), dim3(1024), 0, stream,
                     row_ptr, cv, cvT, Harr, off, out);
}

// Round 7
// 275.466 us; speedup vs baseline: 1.9114x; 1.0052x over previous
//
#include <hip/hip_runtime.h>

#define NN 4096
#define HD 64
#define KNB 15
#define NE 32768
#define NM (NE + NN*KNB)   // 94208 edges total (with duplicates)
#define W64 (NN/64)        // 64 u64 words per bitmap row
#define RB 4               // output rows per block in final_kernel
#define MAXH 96            // max slices per 64-col chunk (max degree bound)
#define NCH (NN/64)        // 64 column chunks

typedef unsigned long long u64;
typedef unsigned int u32;

// order-preserving float->uint map
__device__ __forceinline__ u32 fmapu(float f) {
  int i = __float_as_int(f);
  return (u32)(i ^ ((i >> 31) | 0x80000000));
}

__device__ __forceinline__ float dot64(const float* __restrict__ a,
                                       const float* __restrict__ b) {
  const float4* a4 = (const float4*)a;
  const float4* b4 = (const float4*)b;
  float s = 0.f;
#pragma unroll
  for (int t = 0; t < 16; ++t) {
    float4 x = a4[t], y = b4[t];
    s = fmaf(x.x, y.x, s); s = fmaf(x.y, y.y, s);
    s = fmaf(x.z, y.z, s); s = fmaf(x.w, y.w, s);
  }
  return s;
}

__device__ __forceinline__ void edge_decode(int m, const int* __restrict__ ei,
                                            const int* __restrict__ knn_idx,
                                            int& s, int& d) {
  if (m < NE) { s = ei[m]; d = ei[NE + m]; }
  else { int mm = m - NE; s = mm / KNB; d = knn_idx[mm]; }
}

// ---------- KNN (+ workspace zeroing folded in): block per node ------------
// Radix binary-search for the 15th-smallest distance key.
__global__ __launch_bounds__(256) void knn_kernel(const float* __restrict__ pts,
                                                  int* __restrict__ knn_idx,
                                                  u32* __restrict__ zero_base,
                                                  int zero_n) {
  // fold: zero bR + denom + H (contiguous at ws start); one u32 per thread
  int zi = blockIdx.x * 256 + threadIdx.x;
  if (zi < zero_n) zero_base[zi] = 0u;

  __shared__ u32 s_wcnt[4];
  __shared__ int s_eq[256];
  __shared__ u32 s_cnt[2];   // [0]=strict-less slots, [1]=equal count
  int i = blockIdx.x;
  int tid = threadIdx.x;
  int lane = tid & 63, wv = tid >> 6;
  float px = pts[i*3+0], py = pts[i*3+1], pz = pts[i*3+2];
  // match np: (x*x + y*y) + z*z, no fma contraction
  float sqi = __fadd_rn(__fadd_rn(__fmul_rn(px,px), __fmul_rn(py,py)), __fmul_rn(pz,pz));
  u32 key[16];
#pragma unroll
  for (int s = 0; s < 16; ++s) {
    int j = s*256 + tid;
    float x = pts[j*3+0], y = pts[j*3+1], z = pts[j*3+2];
    float sqj = __fadd_rn(__fadd_rn(__fmul_rn(x,x), __fmul_rn(y,y)), __fmul_rn(z,z));
    // match BLAS fma chain: acc = x*xj; fma(y,..); fma(z,..)
    float dot = fmaf(pz, z, fmaf(py, y, __fmul_rn(px, x)));
    float d2 = __fadd_rn(__fsub_rn(sqi, __fmul_rn(2.0f, dot)), sqj);
    key[s] = (j == i) ? 0xFFFFFFFFu : fmapu(d2);
  }
  // binary search on bits: tau = 15th smallest key
  u32 prefix = 0u;
  for (int b = 31; b >= 0; --b) {
    u32 trial = prefix | (1u << b);
    u32 c = 0;
#pragma unroll
    for (int s = 0; s < 16; ++s) c += (key[s] < trial) ? 1u : 0u;
#pragma unroll
    for (int off = 32; off >= 1; off >>= 1) c += __shfl_xor((int)c, off, 64);
    if (lane == 0) s_wcnt[wv] = c;
    __syncthreads();
    u32 total = s_wcnt[0] + s_wcnt[1] + s_wcnt[2] + s_wcnt[3];
    if (total < KNB) prefix = trial;   // uniform across block
    __syncthreads();
  }
  u32 tau = prefix;
  if (tid == 0) { s_cnt[0] = 0u; s_cnt[1] = 0u; }
  __syncthreads();
#pragma unroll
  for (int s = 0; s < 16; ++s) {
    int j = s*256 + tid;
    if (key[s] < tau) {
      u32 p = atomicAdd(&s_cnt[0], 1u);
      knn_idx[i*KNB + p] = j;
    } else if (key[s] == tau) {
      u32 p = atomicAdd(&s_cnt[1], 1u);
      if (p < 256u) s_eq[p] = j;
    }
  }
  __syncthreads();
  if (tid == 0) {
    int cls = (int)s_cnt[0];
    int ceq = (int)s_cnt[1]; if (ceq > 256) ceq = 256;
    int need = KNB - cls;
    for (int r = 0; r < need; ++r) {      // smallest indices among ties
      int best = 1 << 30, bidx = 0;
      for (int t = 0; t < ceq; ++t) {
        int v = s_eq[t];
        if (v < best) { best = v; bidx = t; }
      }
      s_eq[bidx] = 1 << 30;
      knn_idx[i*KNB + cls + r] = best;
    }
  }
}

// ---------- mark unique edges in row bitmap ----------
__global__ void bitmap_kernel(const int* __restrict__ ei, const int* __restrict__ knn_idx,
                              u64* __restrict__ bR) {
  int m = blockIdx.x * 256 + threadIdx.x;
  if (m >= NM) return;
  int s, d; edge_decode(m, ei, knn_idx, s, d);
  atomicOr(&bR[(size_t)s*W64 + (d >> 6)], 1ull << (d & 63));
}

// ---------- out-degrees from bitmap + per-chunk max degree ----------
__global__ void deg_kernel(const u64* __restrict__ bR, int* __restrict__ outdeg,
                           int* __restrict__ H) {
  int i = blockIdx.x * 256 + threadIdx.x;
  if (i >= NN) return;
  int c = 0;
  for (int w = 0; w < W64; ++w) c += __popcll(bR[(size_t)i*W64 + w]);
  outdeg[i] = c;
  atomicMax(&H[i >> 6], c);
}

// ---------- exclusive scan of outdeg -> row_ptr; scan of H -> off ----------
__global__ __launch_bounds__(1024) void scan_kernel(const int* __restrict__ deg,
                                                    int* __restrict__ ptr,
                                                    int* __restrict__ H,
                                                    int* __restrict__ off) {
  __shared__ int part[1024];
  int t = threadIdx.x;
  int base = t * 4;
  int a0 = deg[base], a1 = deg[base+1], a2 = deg[base+2], a3 = deg[base+3];
  part[t] = a0 + a1 + a2 + a3;
  __syncthreads();
  for (int o = 1; o < 1024; o <<= 1) {
    int v = 0;
    if (t >= o) v = part[t - o];
    __syncthreads();
    if (t >= o) part[t] += v;
    __syncthreads();
  }
  int excl = (t > 0) ? part[t-1] : 0;
  ptr[base]   = excl;
  ptr[base+1] = excl + a0;
  ptr[base+2] = excl + a0 + a1;
  ptr[base+3] = excl + a0 + a1 + a2;
  if (t == 1023) ptr[NN] = part[1023];
  // chunk-height scan on wave 0 (64 lanes exactly)
  if (t < 64) {
    int h = H[t]; if (h > MAXH) h = MAXH;
    H[t] = h;
    int x = h;
#pragma unroll
    for (int o = 1; o < 64; o <<= 1) {
      int v = __shfl_up(x, o, 64);
      if (t >= o) x += v;
    }
    off[t + 1] = x;
    if (t == 0) off[0] = 0;
  }
}

// ---------- CSR fill from bitmap: cols + owner row id ----------
__global__ void fill_kernel(const u64* __restrict__ bR, const int* __restrict__ row_ptr,
                            int* __restrict__ csr_col, int* __restrict__ csr_rowid) {
  int i = blockIdx.x * 256 + threadIdx.x;
  if (i >= NN) return;
  int off = row_ptr[i];
  for (int w = 0; w < W64; ++w) {
    u64 b = bR[(size_t)i*W64 + w];
    while (b) {
      int t = __builtin_ctzll(b); b &= b - 1;
      csr_col[off] = w*64 + t; csr_rowid[off] = i; ++off;
    }
  }
}

// ---------- fused: maxf (register) -> dev = relu(W_phi .) -> q,k ----------
__global__ __launch_bounds__(256) void theta_devqk_kernel(const float* __restrict__ pts,
    const int* __restrict__ row_ptr, const int* __restrict__ csr_col,
    const float* __restrict__ Wt, const float* __restrict__ bt,
    const float* __restrict__ Wp, const float* __restrict__ bp,
    const float* __restrict__ Wq, const float* __restrict__ bq,
    const float* __restrict__ Wk, const float* __restrict__ bk,
    float* __restrict__ qv, float* __restrict__ kv) {
  __shared__ float mf[4][HD];
  __shared__ float dv[4][HD];
  int lane = threadIdx.x & 63, sub = threadIdx.x >> 6;
  int i = blockIdx.x * 4 + sub;
  float w0 = Wt[lane*3+0], w1 = Wt[lane*3+1], w2 = Wt[lane*3+2], bb = bt[lane];
  float px = pts[i*3+0], py = pts[i*3+1], pz = pts[i*3+2];
  float m = -INFINITY;
  int rb = row_ptr[i], re = row_ptr[i+1];
  for (int e = rb; e < re; ++e) {
    int d = csr_col[e];
    float dx = __fsub_rn(pts[d*3+0], px);
    float dy = __fsub_rn(pts[d*3+1], py);
    float dz = __fsub_rn(pts[d*3+2], pz);
    float t = fmaf(dz, w2, fmaf(dy, w1, __fmul_rn(dx, w0)));
    m = fmaxf(m, __fadd_rn(t, bb));
  }
  mf[sub][lane] = m;
  __syncthreads();
  float a = 0.f;
#pragma unroll
  for (int t = 0; t < HD; ++t) a = fmaf(Wp[lane*HD + t], mf[sub][t], a);
  float dvv = a + bp[lane];
  dv[sub][lane] = dvv > 0.f ? dvv : 0.f;
  __syncthreads();
  float aq = 0.f, ak = 0.f;
#pragma unroll
  for (int t = 0; t < HD; ++t) {
    float x = dv[sub][t];
    aq = fmaf(Wq[lane*HD + t], x, aq);
    ak = fmaf(Wk[lane*HD + t], x, ak);
  }
  qv[(size_t)i*HD + lane] = aq + bq[lane];
  kv[(size_t)i*HD + lane] = ak + bk[lane];
}

// ---------- fused denom (raw edges) + UNNORMALIZED vals (unique edges) ------
// Softmax division is deferred to final_kernel: A_s[i,j] =
//   (sum_l e~_jl * T~[i,l]) / (denom_i * denom_j), so vals needn't wait on denom.
__global__ void vals_kernel(const int* __restrict__ ei, const int* __restrict__ knn_idx,
    const int* __restrict__ row_ptr,
    const int* __restrict__ csr_col, const int* __restrict__ csr_rowid,
    const float* __restrict__ qv, const float* __restrict__ kv,
    float* __restrict__ denom, const int* __restrict__ off,
    uint2* __restrict__ cv, uint2* __restrict__ cvT) {
  int half = gridDim.x >> 1;
  if ((int)blockIdx.x < half) {
    // denom over ALL M raw edges (duplicates count)
    int m = blockIdx.x * 256 + threadIdx.x;
    if (m >= NM) return;
    int s, d; edge_decode(m, ei, knn_idx, s, d);
    float e = expf(dot64(qv + (size_t)d*HD, kv + (size_t)s*HD));
    atomicAdd(&denom[s], e);
  } else {
    // unnormalized e~ for unique edges -> CSR stream + sliced-ELL
    int e = (blockIdx.x - half) * 256 + threadIdx.x;
    if (e >= row_ptr[NN]) return;
    int i = csr_rowid[e], col = csr_col[e];
    float s = dot64(qv + (size_t)col*HD, kv + (size_t)i*HD);
    float val = expf(s);
    uint2 u = make_uint2((u32)col, __float_as_uint(val));
    cv[e] = u;
    int sidx = e - row_ptr[i];
    if (sidx < MAXH)
      cvT[(((size_t)off[i >> 6] + sidx) << 6) + (i & 63)] = u;
  }
}

// ---------- A_s rows [i0,i0+4): Phase A scatter into packed float4 LDS, ----
// Phase B coalesced sliced-ELL gather (deg-guarded, register accumulators),
// final division by denom_i * denom_j at store.
__global__ __launch_bounds__(1024, 8) void final_kernel(
    const int* __restrict__ row_ptr, const uint2* __restrict__ cv,
    const uint2* __restrict__ cvT, const int* __restrict__ H,
    const int* __restrict__ off, const float* __restrict__ denom,
    float* __restrict__ out) {
  __shared__ float4 T4[NN];   // 64KB packed T~[l][0..3]
  int tid = threadIdx.x;
  int i0 = blockIdx.x * RB;
  float4 z4 = make_float4(0.f, 0.f, 0.f, 0.f);
  for (int t = tid; t < NN; t += 1024) T4[t] = z4;
  __syncthreads();
  int w = tid >> 6, lane = tid & 63;
  float* Tf = (float*)T4;
  // Phase A: 4 waves per output row r; T~_r[l] += e~[i0+r,k] for l in out(k)
  {
    int r = w & (RB - 1);
    int i = i0 + r;
    int rb = row_ptr[i], re = row_ptr[i+1];
    for (int idx = rb + (w >> 2); idx < re; idx += RB) {
      uint2 e = cv[idx];
      int k = (int)e.x; float wv = __uint_as_float(e.y);
      int kb = row_ptr[k], ke = row_ptr[k+1];
      for (int t = kb + lane; t < ke; t += 64)
        atomicAdd(&Tf[(int)cv[t].x * 4 + r], wv);
    }
  }
  __syncthreads();
  // Phase B: thread owns cols {tid + g*1024}; coalesced ELL slices, one
  // b128 T-read per visit; per-lane degree guard skips padding entirely.
  float acc[4][RB];
#pragma unroll
  for (int g = 0; g < 4; ++g)
#pragma unroll
    for (int r = 0; r < RB; ++r) acc[g][r] = 0.f;
#pragma unroll
  for (int g = 0; g < 4; ++g) {
    int j = tid + g * 1024;
    int c = j >> 6;                 // wave-uniform chunk
    int Hc = H[c];
    int dj = row_ptr[j+1] - row_ptr[j];
    const uint2* p = cvT + (((size_t)off[c]) << 6) + (j & 63);
#pragma unroll 2
    for (int s = 0; s < Hc; ++s) {
      if (s < dj) {
        uint2 e = p[(size_t)s << 6];  // coalesced: lane-consecutive
        float v = __uint_as_float(e.y);
        float4 tv = T4[(int)e.x];
        acc[g][0] = fmaf(v, tv.x, acc[g][0]);
        acc[g][1] = fmaf(v, tv.y, acc[g][1]);
        acc[g][2] = fmaf(v, tv.z, acc[g][2]);
        acc[g][3] = fmaf(v, tv.w, acc[g][3]);
      }
    }
  }
  float rden[RB];
#pragma unroll
  for (int r = 0; r < RB; ++r) rden[r] = 1.0f / denom[i0 + r];
#pragma unroll
  for (int g = 0; g < 4; ++g) {
    int j = tid + g * 1024;
    float dj_den = denom[j];
#pragma unroll
    for (int r = 0; r < RB; ++r)
      out[(size_t)(i0 + r) * NN + j] = acc[g][r] * rden[r] / dj_den;
  }
}

extern "C" void kernel_launch(void* const* d_in, const int* in_sizes, int n_in,
                              void* d_out, int out_size, void* d_ws, size_t ws_size,
                              hipStream_t stream) {
  (void)in_sizes; (void)n_in; (void)out_size;
  const float* pts = (const float*)d_in[0];
  // d_in[1] = features: unused by the reference
  const int* ei = (const int*)d_in[2];
  const float* Wt = (const float*)d_in[3];
  const float* bt = (const float*)d_in[4];
  const float* Wp = (const float*)d_in[5];
  const float* bp = (const float*)d_in[6];
  const float* Wq = (const float*)d_in[7];
  const float* bq = (const float*)d_in[8];
  const float* Wk = (const float*)d_in[9];
  const float* bk = (const float*)d_in[10];
  float* out = (float*)d_out;

  char* w = (char*)d_ws;
  // zeroed region first (contiguous): bR, denom, H
  u64* bR = (u64*)w;        w += (size_t)NN*W64*8;       // 2MB
  float* denom = (float*)w; w += (size_t)NN*4;           // 16KB
  int* H = (int*)w;         w += (size_t)NCH*4;          // 256B
  int* off = (int*)w;       w += (size_t)(NCH+4)*4;
  float* qv = (float*)w;    w += (size_t)NN*HD*4;        // 1MB
  float* kv = (float*)w;    w += (size_t)NN*HD*4;        // 1MB
  int* knn_idx = (int*)w;   w += (size_t)NN*KNB*4;
  int* outdeg = (int*)w;    w += (size_t)NN*4;
  int* row_ptr = (int*)w;   w += (size_t)(NN+4)*4;
  int* csr_col = (int*)w;   w += (size_t)NM*4;
  int* csr_rowid = (int*)w; w += (size_t)NM*4;
  uint2* cv = (uint2*)w;    w += (size_t)NM*8;
  uint2* cvT = (uint2*)w;   w += (size_t)NCH*MAXH*64*8;  // 3MB (padding never read)
  if ((size_t)(w - (char*)d_ws) > ws_size) return;  // insufficient scratch

  int zero_u32s = (int)(((size_t)NN*W64*8 + (size_t)NN*4 + (size_t)NCH*4) / 4);
  hipLaunchKernelGGL(knn_kernel, dim3(NN), dim3(256), 0, stream,
                     pts, knn_idx, (u32*)d_ws, zero_u32s);
  hipLaunchKernelGGL(bitmap_kernel, dim3((NM+255)/256), dim3(256), 0, stream,
                     ei, knn_idx, bR);
  hipLaunchKernelGGL(deg_kernel, dim3(NN/256), dim3(256), 0, stream, bR, outdeg, H);
  hipLaunchKernelGGL(scan_kernel, dim3(1), dim3(1024), 0, stream,
                     outdeg, row_ptr, H, off);
  hipLaunchKernelGGL(fill_kernel, dim3(NN/256), dim3(256), 0, stream,
                     bR, row_ptr, csr_col, csr_rowid);
  hipLaunchKernelGGL(theta_devqk_kernel, dim3(NN/4), dim3(256), 0, stream,
                     pts, row_ptr, csr_col, Wt, bt, Wp, bp, Wq, bq, Wk, bk, qv, kv);
  int vhalf = (NM+255)/256;
  hipLaunchKernelGGL(vals_kernel, dim3(2*vhalf), dim3(256), 0, stream,
                     ei, knn_idx, row_ptr, csr_col, csr_rowid, qv, kv,
                     denom, off, cv, cvT);
  hipLaunchKernelGGL(final_kernel, dim3(NN/RB), dim3(1024), 0, stream,
                     row_ptr, cv, cvT, H, off, denom, out);
}

// Round 8
// 232.706 us; speedup vs baseline: 2.2626x; 1.1838x over previous
//
#include <hip/hip_runtime.h>

#define NN 4096
#define HD 64
#define KNB 15
#define NE 32768
#define NM (NE + NN*KNB)   // 94208 edges total (with duplicates)
#define W64 (NN/64)        // 64 u64 words per bitmap row
#define RB 4               // output rows per block in final_kernel
#define MAXH 96            // max slices per 64-col chunk (max degree bound)
#define NCH (NN/64)        // 64 column chunks
#define TDP 65             // padded LDS stride for 64x64 weights (conflict-free)

typedef unsigned long long u64;
typedef unsigned int u32;

// order-preserving float->uint map
__device__ __forceinline__ u32 fmapu(float f) {
  int i = __float_as_int(f);
  return (u32)(i ^ ((i >> 31) | 0x80000000));
}

__device__ __forceinline__ float dot64(const float* __restrict__ a,
                                       const float* __restrict__ b) {
  const float4* a4 = (const float4*)a;
  const float4* b4 = (const float4*)b;
  float s = 0.f;
#pragma unroll
  for (int t = 0; t < 16; ++t) {
    float4 x = a4[t], y = b4[t];
    s = fmaf(x.x, y.x, s); s = fmaf(x.y, y.y, s);
    s = fmaf(x.z, y.z, s); s = fmaf(x.w, y.w, s);
  }
  return s;
}

__device__ __forceinline__ void edge_decode(int m, const int* __restrict__ ei,
                                            const int* __restrict__ knn_idx,
                                            int& s, int& d) {
  if (m < NE) { s = ei[m]; d = ei[NE + m]; }
  else { int mm = m - NE; s = mm / KNB; d = knn_idx[mm]; }
}

// ---------- KNN (+ workspace zeroing folded in): block per node ------------
// tau = 15th-smallest distance key via 4-round radix-256 histogram select.
__global__ __launch_bounds__(256) void knn_kernel(const float* __restrict__ pts,
                                                  int* __restrict__ knn_idx,
                                                  u32* __restrict__ zero_base,
                                                  int zero_n) {
  // fold: zero bR + denom + H (contiguous at ws start); one u32 per thread
  int zi = blockIdx.x * 256 + threadIdx.x;
  if (zi < zero_n) zero_base[zi] = 0u;

  __shared__ int hist[4][256];   // per-wave histograms (contention /4)
  __shared__ int s_eq[256];
  __shared__ u32 s_cnt[2];       // [0]=strict-less slots, [1]=equal count
  __shared__ int s_bin, s_below, s_need;
  int i = blockIdx.x;
  int tid = threadIdx.x;
  int lane = tid & 63, wv = tid >> 6;
  float px = pts[i*3+0], py = pts[i*3+1], pz = pts[i*3+2];
  // match np: (x*x + y*y) + z*z, no fma contraction
  float sqi = __fadd_rn(__fadd_rn(__fmul_rn(px,px), __fmul_rn(py,py)), __fmul_rn(pz,pz));
  u32 key[16];
#pragma unroll
  for (int s = 0; s < 16; ++s) {
    int j = s*256 + tid;
    float x = pts[j*3+0], y = pts[j*3+1], z = pts[j*3+2];
    float sqj = __fadd_rn(__fadd_rn(__fmul_rn(x,x), __fmul_rn(y,y)), __fmul_rn(z,z));
    // match BLAS fma chain: acc = x*xj; fma(y,..); fma(z,..)
    float dot = fmaf(pz, z, fmaf(py, y, __fmul_rn(px, x)));
    float d2 = __fadd_rn(__fsub_rn(sqi, __fmul_rn(2.0f, dot)), sqj);
    key[s] = (j == i) ? 0xFFFFFFFFu : fmapu(d2);
  }
  if (tid == 0) s_need = KNB;
  u32 prefix = 0u;
#pragma unroll
  for (int r = 0; r < 4; ++r) {
    int shift = 24 - 8*r;
    for (int t = tid; t < 1024; t += 256) ((int*)hist)[t] = 0;
    __syncthreads();
    u32 mask_hi = (r == 0) ? 0u : (0xFFFFFFFFu << (shift + 8));
#pragma unroll
    for (int s = 0; s < 16; ++s) {
      if ((key[s] & mask_hi) == prefix)
        atomicAdd(&hist[wv][(key[s] >> shift) & 255], 1);
    }
    __syncthreads();
    if (tid < 64) {   // exactly wave 0: scan 256 bins, find bin of rank s_need
      int b0 = tid * 4;
      int c0 = hist[0][b0  ]+hist[1][b0  ]+hist[2][b0  ]+hist[3][b0  ];
      int c1 = hist[0][b0+1]+hist[1][b0+1]+hist[2][b0+1]+hist[3][b0+1];
      int c2 = hist[0][b0+2]+hist[1][b0+2]+hist[2][b0+2]+hist[3][b0+2];
      int c3 = hist[0][b0+3]+hist[1][b0+3]+hist[2][b0+3]+hist[3][b0+3];
      int need = s_need;          // wave-lockstep: read before any lane writes
      int tot = c0 + c1 + c2 + c3;
      int x = tot;
#pragma unroll
      for (int o = 1; o < 64; o <<= 1) {
        int v = __shfl_up(x, o, 64);
        if (tid >= o) x += v;
      }
      int cum = x - tot;          // exclusive prefix for this lane's first bin
      if (need > cum && need <= cum + c0) { s_bin = b0;   s_below = cum; }
      cum += c0;
      if (need > cum && need <= cum + c1) { s_bin = b0+1; s_below = cum; }
      cum += c1;
      if (need > cum && need <= cum + c2) { s_bin = b0+2; s_below = cum; }
      cum += c2;
      if (need > cum && need <= cum + c3) { s_bin = b0+3; s_below = cum; }
    }
    __syncthreads();
    prefix |= (u32)s_bin << shift;
    if (tid == 0) s_need = s_need - s_below;
    // next round's post-zero barrier orders s_need for wave 0's next read
  }
  u32 tau = prefix;
  if (tid == 0) { s_cnt[0] = 0u; s_cnt[1] = 0u; }
  __syncthreads();
#pragma unroll
  for (int s = 0; s < 16; ++s) {
    int j = s*256 + tid;
    if (key[s] < tau) {
      u32 p = atomicAdd(&s_cnt[0], 1u);
      knn_idx[i*KNB + p] = j;
    } else if (key[s] == tau) {
      u32 p = atomicAdd(&s_cnt[1], 1u);
      if (p < 256u) s_eq[p] = j;
    }
  }
  __syncthreads();
  if (tid == 0) {
    int cls = (int)s_cnt[0];
    int ceq = (int)s_cnt[1]; if (ceq > 256) ceq = 256;
    int need = KNB - cls;
    for (int r = 0; r < need; ++r) {      // smallest indices among ties
      int best = 1 << 30, bidx = 0;
      for (int t = 0; t < ceq; ++t) {
        int v = s_eq[t];
        if (v < best) { best = v; bidx = t; }
      }
      s_eq[bidx] = 1 << 30;
      knn_idx[i*KNB + cls + r] = best;
    }
  }
}

// ---------- mark unique edges in row bitmap ----------
__global__ void bitmap_kernel(const int* __restrict__ ei, const int* __restrict__ knn_idx,
                              u64* __restrict__ bR) {
  int m = blockIdx.x * 256 + threadIdx.x;
  if (m >= NM) return;
  int s, d; edge_decode(m, ei, knn_idx, s, d);
  atomicOr(&bR[(size_t)s*W64 + (d >> 6)], 1ull << (d & 63));
}

// ---------- out-degrees from bitmap + per-chunk max degree ----------
__global__ void deg_kernel(const u64* __restrict__ bR, int* __restrict__ outdeg,
                           int* __restrict__ H) {
  int i = blockIdx.x * 256 + threadIdx.x;
  if (i >= NN) return;
  int c = 0;
  for (int w = 0; w < W64; ++w) c += __popcll(bR[(size_t)i*W64 + w]);
  outdeg[i] = c;
  atomicMax(&H[i >> 6], c);
}

// ---------- exclusive scan of outdeg -> row_ptr; scan of H -> off ----------
__global__ __launch_bounds__(1024) void scan_kernel(const int* __restrict__ deg,
                                                    int* __restrict__ ptr,
                                                    int* __restrict__ H,
                                                    int* __restrict__ off) {
  __shared__ int part[1024];
  int t = threadIdx.x;
  int base = t * 4;
  int a0 = deg[base], a1 = deg[base+1], a2 = deg[base+2], a3 = deg[base+3];
  part[t] = a0 + a1 + a2 + a3;
  __syncthreads();
  for (int o = 1; o < 1024; o <<= 1) {
    int v = 0;
    if (t >= o) v = part[t - o];
    __syncthreads();
    if (t >= o) part[t] += v;
    __syncthreads();
  }
  int excl = (t > 0) ? part[t-1] : 0;
  ptr[base]   = excl;
  ptr[base+1] = excl + a0;
  ptr[base+2] = excl + a0 + a1;
  ptr[base+3] = excl + a0 + a1 + a2;
  if (t == 1023) ptr[NN] = part[1023];
  // chunk-height scan on wave 0 (64 lanes exactly)
  if (t < 64) {
    int h = H[t]; if (h > MAXH) h = MAXH;
    H[t] = h;
    int x = h;
#pragma unroll
    for (int o = 1; o < 64; o <<= 1) {
      int v = __shfl_up(x, o, 64);
      if (t >= o) x += v;
    }
    off[t + 1] = x;
    if (t == 0) off[0] = 0;
  }
}

// ---------- CSR fill from bitmap: cols + owner row id ----------
__global__ void fill_kernel(const u64* __restrict__ bR, const int* __restrict__ row_ptr,
                            int* __restrict__ csr_col, int* __restrict__ csr_rowid) {
  int i = blockIdx.x * 256 + threadIdx.x;
  if (i >= NN) return;
  int off = row_ptr[i];
  for (int w = 0; w < W64; ++w) {
    u64 b = bR[(size_t)i*W64 + w];
    while (b) {
      int t = __builtin_ctzll(b); b &= b - 1;
      csr_col[off] = w*64 + t; csr_rowid[off] = i; ++off;
    }
  }
}

// ---------- fused: maxf (register) -> dev = relu(W_phi .) -> q,k ----------
// Weights staged in LDS with stride-65 padding: per-lane row reads are
// bank-conflict-free instead of 64-way L1 line splits.
__global__ __launch_bounds__(512) void theta_devqk_kernel(const float* __restrict__ pts,
    const int* __restrict__ row_ptr, const int* __restrict__ csr_col,
    const float* __restrict__ Wt, const float* __restrict__ bt,
    const float* __restrict__ Wp, const float* __restrict__ bp,
    const float* __restrict__ Wq, const float* __restrict__ bq,
    const float* __restrict__ Wk, const float* __restrict__ bk,
    float* __restrict__ qv, float* __restrict__ kv) {
  __shared__ float Wps[HD*TDP], Wqs[HD*TDP], Wks[HD*TDP];  // 3 x 16.25KB
  __shared__ float mf[8][HD];
  __shared__ float dv[8][HD];
  int tid = threadIdx.x;
  for (int m = tid; m < HD*HD; m += 512) {
    int row = m >> 6, col = m & 63;
    Wps[row*TDP + col] = Wp[m];
    Wqs[row*TDP + col] = Wq[m];
    Wks[row*TDP + col] = Wk[m];
  }
  int lane = tid & 63, sub = tid >> 6;
  int i = blockIdx.x * 8 + sub;
  float w0 = Wt[lane*3+0], w1 = Wt[lane*3+1], w2 = Wt[lane*3+2], bb = bt[lane];
  float px = pts[i*3+0], py = pts[i*3+1], pz = pts[i*3+2];
  float m = -INFINITY;
  int rb = row_ptr[i], re = row_ptr[i+1];
  for (int e = rb; e < re; ++e) {
    int d = csr_col[e];
    float dx = __fsub_rn(pts[d*3+0], px);
    float dy = __fsub_rn(pts[d*3+1], py);
    float dz = __fsub_rn(pts[d*3+2], pz);
    float t = fmaf(dz, w2, fmaf(dy, w1, __fmul_rn(dx, w0)));
    m = fmaxf(m, __fadd_rn(t, bb));
  }
  mf[sub][lane] = m;
  __syncthreads();   // also covers weight staging
  float a = 0.f;
#pragma unroll
  for (int t = 0; t < HD; ++t) a = fmaf(Wps[lane*TDP + t], mf[sub][t], a);
  float dvv = a + bp[lane];
  dv[sub][lane] = dvv > 0.f ? dvv : 0.f;
  __syncthreads();
  float aq = 0.f, ak = 0.f;
#pragma unroll
  for (int t = 0; t < HD; ++t) {
    float x = dv[sub][t];
    aq = fmaf(Wqs[lane*TDP + t], x, aq);
    ak = fmaf(Wks[lane*TDP + t], x, ak);
  }
  qv[(size_t)i*HD + lane] = aq + bq[lane];
  kv[(size_t)i*HD + lane] = ak + bk[lane];
}

// ---------- fused denom (raw edges) + UNNORMALIZED vals (unique edges) ------
// Softmax division is deferred to final_kernel: A_s[i,j] =
//   (sum_l e~_jl * T~[i,l]) / (denom_i * denom_j), so vals needn't wait on denom.
__global__ void vals_kernel(const int* __restrict__ ei, const int* __restrict__ knn_idx,
    const int* __restrict__ row_ptr,
    const int* __restrict__ csr_col, const int* __restrict__ csr_rowid,
    const float* __restrict__ qv, const float* __restrict__ kv,
    float* __restrict__ denom, const int* __restrict__ off,
    uint2* __restrict__ cv, uint2* __restrict__ cvT) {
  int half = gridDim.x >> 1;
  if ((int)blockIdx.x < half) {
    // denom over ALL M raw edges (duplicates count)
    int m = blockIdx.x * 256 + threadIdx.x;
    if (m >= NM) return;
    int s, d; edge_decode(m, ei, knn_idx, s, d);
    float e = expf(dot64(qv + (size_t)d*HD, kv + (size_t)s*HD));
    atomicAdd(&denom[s], e);
  } else {
    // unnormalized e~ for unique edges -> CSR stream + sliced-ELL
    int e = (blockIdx.x - half) * 256 + threadIdx.x;
    if (e >= row_ptr[NN]) return;
    int i = csr_rowid[e], col = csr_col[e];
    float s = dot64(qv + (size_t)col*HD, kv + (size_t)i*HD);
    float val = expf(s);
    uint2 u = make_uint2((u32)col, __float_as_uint(val));
    cv[e] = u;
    int sidx = e - row_ptr[i];
    if (sidx < MAXH)
      cvT[(((size_t)off[i >> 6] + sidx) << 6) + (i & 63)] = u;
  }
}

// ---------- A_s rows [i0,i0+4): Phase A scatter into packed float4 LDS, ----
// Phase B coalesced sliced-ELL gather, 4-deep software-pipelined batches,
// final division by denom_i * denom_j at store.
__global__ __launch_bounds__(1024, 8) void final_kernel(
    const int* __restrict__ row_ptr, const uint2* __restrict__ cv,
    const uint2* __restrict__ cvT, const int* __restrict__ H,
    const int* __restrict__ off, const float* __restrict__ denom,
    float* __restrict__ out) {
  __shared__ float4 T4[NN];   // 64KB packed T~[l][0..3]
  int tid = threadIdx.x;
  int i0 = blockIdx.x * RB;
  float4 z4 = make_float4(0.f, 0.f, 0.f, 0.f);
  for (int t = tid; t < NN; t += 1024) T4[t] = z4;
  __syncthreads();
  int w = tid >> 6, lane = tid & 63;
  float* Tf = (float*)T4;
  // Phase A: 4 waves per output row r; T~_r[l] += e~[i0+r,k] for l in out(k)
  {
    int r = w & (RB - 1);
    int i = i0 + r;
    int rb = row_ptr[i], re = row_ptr[i+1];
    for (int idx = rb + (w >> 2); idx < re; idx += RB) {
      uint2 e = cv[idx];
      int k = (int)e.x; float wv = __uint_as_float(e.y);
      int kb = row_ptr[k], ke = row_ptr[k+1];
      for (int t = kb + lane; t < ke; t += 64)
        atomicAdd(&Tf[(int)cv[t].x * 4 + r], wv);
    }
  }
  __syncthreads();
  // Phase B: thread owns cols {tid + g*1024}; 4-deep batches give 4
  // independent load->ds_read->fma chains in flight.
  float acc[4][RB];
#pragma unroll
  for (int g = 0; g < 4; ++g)
#pragma unroll
    for (int r = 0; r < RB; ++r) acc[g][r] = 0.f;
#pragma unroll
  for (int g = 0; g < 4; ++g) {
    int j = tid + g * 1024;
    int c = j >> 6;                 // wave-uniform chunk
    int dj = row_ptr[j+1] - row_ptr[j];
    const uint2* p = cvT + (((size_t)off[c]) << 6) + (j & 63);
    int s = 0;
    for (; s + 4 <= dj; s += 4) {
      uint2 e0 = p[(size_t)(s+0) << 6];
      uint2 e1 = p[(size_t)(s+1) << 6];
      uint2 e2 = p[(size_t)(s+2) << 6];
      uint2 e3 = p[(size_t)(s+3) << 6];
      float4 t0 = T4[(int)e0.x];
      float4 t1 = T4[(int)e1.x];
      float4 t2 = T4[(int)e2.x];
      float4 t3 = T4[(int)e3.x];
      float v0 = __uint_as_float(e0.y), v1 = __uint_as_float(e1.y);
      float v2 = __uint_as_float(e2.y), v3 = __uint_as_float(e3.y);
      acc[g][0] = fmaf(v0, t0.x, acc[g][0]); acc[g][1] = fmaf(v0, t0.y, acc[g][1]);
      acc[g][2] = fmaf(v0, t0.z, acc[g][2]); acc[g][3] = fmaf(v0, t0.w, acc[g][3]);
      acc[g][0] = fmaf(v1, t1.x, acc[g][0]); acc[g][1] = fmaf(v1, t1.y, acc[g][1]);
      acc[g][2] = fmaf(v1, t1.z, acc[g][2]); acc[g][3] = fmaf(v1, t1.w, acc[g][3]);
      acc[g][0] = fmaf(v2, t2.x, acc[g][0]); acc[g][1] = fmaf(v2, t2.y, acc[g][1]);
      acc[g][2] = fmaf(v2, t2.z, acc[g][2]); acc[g][3] = fmaf(v2, t2.w, acc[g][3]);
      acc[g][0] = fmaf(v3, t3.x, acc[g][0]); acc[g][1] = fmaf(v3, t3.y, acc[g][1]);
      acc[g][2] = fmaf(v3, t3.z, acc[g][2]); acc[g][3] = fmaf(v3, t3.w, acc[g][3]);
    }
    for (; s < dj; ++s) {
      uint2 e = p[(size_t)s << 6];
      float v = __uint_as_float(e.y);
      float4 tv = T4[(int)e.x];
      acc[g][0] = fmaf(v, tv.x, acc[g][0]);
      acc[g][1] = fmaf(v, tv.y, acc[g][1]);
      acc[g][2] = fmaf(v, tv.z, acc[g][2]);
      acc[g][3] = fmaf(v, tv.w, acc[g][3]);
    }
  }
  float rden[RB];
#pragma unroll
  for (int r = 0; r < RB; ++r) rden[r] = 1.0f / denom[i0 + r];
#pragma unroll
  for (int g = 0; g < 4; ++g) {
    int j = tid + g * 1024;
    float dj_den = denom[j];
#pragma unroll
    for (int r = 0; r < RB; ++r)
      out[(size_t)(i0 + r) * NN + j] = acc[g][r] * rden[r] / dj_den;
  }
}

extern "C" void kernel_launch(void* const* d_in, const int* in_sizes, int n_in,
                              void* d_out, int out_size, void* d_ws, size_t ws_size,
                              hipStream_t stream) {
  (void)in_sizes; (void)n_in; (void)out_size;
  const float* pts = (const float*)d_in[0];
  // d_in[1] = features: unused by the reference
  const int* ei = (const int*)d_in[2];
  const float* Wt = (const float*)d_in[3];
  const float* bt = (const float*)d_in[4];
  const float* Wp = (const float*)d_in[5];
  const float* bp = (const float*)d_in[6];
  const float* Wq = (const float*)d_in[7];
  const float* bq = (const float*)d_in[8];
  const float* Wk = (const float*)d_in[9];
  const float* bk = (const float*)d_in[10];
  float* out = (float*)d_out;

  char* w = (char*)d_ws;
  // zeroed region first (contiguous): bR, denom, H
  u64* bR = (u64*)w;        w += (size_t)NN*W64*8;       // 2MB
  float* denom = (float*)w; w += (size_t)NN*4;           // 16KB
  int* H = (int*)w;         w += (size_t)NCH*4;          // 256B
  int* off = (int*)w;       w += (size_t)(NCH+4)*4;
  float* qv = (float*)w;    w += (size_t)NN*HD*4;        // 1MB
  float* kv = (float*)w;    w += (size_t)NN*HD*4;        // 1MB
  int* knn_idx = (int*)w;   w += (size_t)NN*KNB*4;
  int* outdeg = (int*)w;    w += (size_t)NN*4;
  int* row_ptr = (int*)w;   w += (size_t)(NN+4)*4;
  int* csr_col = (int*)w;   w += (size_t)NM*4;
  int* csr_rowid = (int*)w; w += (size_t)NM*4;
  uint2* cv = (uint2*)w;    w += (size_t)NM*8;
  uint2* cvT = (uint2*)w;   w += (size_t)NCH*MAXH*64*8;  // 3MB (padding never read)
  if ((size_t)(w - (char*)d_ws) > ws_size) return;  // insufficient scratch

  int zero_u32s = (int)(((size_t)NN*W64*8 + (size_t)NN*4 + (size_t)NCH*4) / 4);
  hipLaunchKernelGGL(knn_kernel, dim3(NN), dim3(256), 0, stream,
                     pts, knn_idx, (u32*)d_ws, zero_u32s);
  hipLaunchKernelGGL(bitmap_kernel, dim3((NM+255)/256), dim3(256), 0, stream,
                     ei, knn_idx, bR);
  hipLaunchKernelGGL(deg_kernel, dim3(NN/256), dim3(256), 0, stream, bR, outdeg, H);
  hipLaunchKernelGGL(scan_kernel, dim3(1), dim3(1024), 0, stream,
                     outdeg, row_ptr, H, off);
  hipLaunchKernelGGL(fill_kernel, dim3(NN/256), dim3(256), 0, stream,
                     bR, row_ptr, csr_col, csr_rowid);
  hipLaunchKernelGGL(theta_devqk_kernel, dim3(NN/8), dim3(512), 0, stream,
                     pts, row_ptr, csr_col, Wt, bt, Wp, bp, Wq, bq, Wk, bk, qv, kv);
  int vhalf = (NM+255)/256;
  hipLaunchKernelGGL(vals_kernel, dim3(2*vhalf), dim3(256), 0, stream,
                     ei, knn_idx, row_ptr, csr_col, csr_rowid, qv, kv,
                     denom, off, cv, cvT);
  hipLaunchKernelGGL(final_kernel, dim3(NN/RB), dim3(1024), 0, stream,
                     row_ptr, cv, cvT, H, off, denom, out);
}

// Round 9
// 184.430 us; speedup vs baseline: 2.8549x; 1.2618x over previous
//
#include <hip/hip_runtime.h>

#define NN 4096
#define HD 64
#define KNB 15
#define NE 32768
#define NM (NE + NN*KNB)   // 94208 edges total (with duplicates)
#define W64 (NN/64)        // 64 u64 words per bitmap row
#define RB 4               // output rows per block in final_kernel
#define MAXH 96            // ELL pitch: max slices per 64-col chunk
#define NCH (NN/64)        // 64 column chunks
#define TDP 65             // padded LDS stride for 64x64 weights (conflict-free)

typedef unsigned long long u64;
typedef unsigned int u32;

// order-preserving float->uint map
__device__ __forceinline__ u32 fmapu(float f) {
  int i = __float_as_int(f);
  return (u32)(i ^ ((i >> 31) | 0x80000000));
}

__device__ __forceinline__ float dot64(const float* __restrict__ a,
                                       const float* __restrict__ b) {
  const float4* a4 = (const float4*)a;
  const float4* b4 = (const float4*)b;
  float s = 0.f;
#pragma unroll
  for (int t = 0; t < 16; ++t) {
    float4 x = a4[t], y = b4[t];
    s = fmaf(x.x, y.x, s); s = fmaf(x.y, y.y, s);
    s = fmaf(x.z, y.z, s); s = fmaf(x.w, y.w, s);
  }
  return s;
}

__device__ __forceinline__ void edge_decode(int m, const int* __restrict__ ei,
                                            const int* __restrict__ knn_idx,
                                            int& s, int& d) {
  if (m < NE) { s = ei[m]; d = ei[NE + m]; }
  else { int mm = m - NE; s = mm / KNB; d = knn_idx[mm]; }
}

// ---------- KNN (+ workspace zeroing folded in): block per node ------------
// tau = 15th-smallest distance key via 4-round radix-256 histogram select.
__global__ __launch_bounds__(256) void knn_kernel(const float* __restrict__ pts,
                                                  int* __restrict__ knn_idx,
                                                  u32* __restrict__ zero_base,
                                                  int zero_n) {
  // fold: zero bR + denom (contiguous at ws start); one u32 per thread
  int zi = blockIdx.x * 256 + threadIdx.x;
  if (zi < zero_n) zero_base[zi] = 0u;

  __shared__ int hist[4][256];   // per-wave histograms (contention /4)
  __shared__ int s_eq[256];
  __shared__ u32 s_cnt[2];       // [0]=strict-less slots, [1]=equal count
  __shared__ int s_bin, s_below, s_need;
  int i = blockIdx.x;
  int tid = threadIdx.x;
  int lane = tid & 63, wv = tid >> 6;
  float px = pts[i*3+0], py = pts[i*3+1], pz = pts[i*3+2];
  // match np: (x*x + y*y) + z*z, no fma contraction
  float sqi = __fadd_rn(__fadd_rn(__fmul_rn(px,px), __fmul_rn(py,py)), __fmul_rn(pz,pz));
  u32 key[16];
#pragma unroll
  for (int s = 0; s < 16; ++s) {
    int j = s*256 + tid;
    float x = pts[j*3+0], y = pts[j*3+1], z = pts[j*3+2];
    float sqj = __fadd_rn(__fadd_rn(__fmul_rn(x,x), __fmul_rn(y,y)), __fmul_rn(z,z));
    // match BLAS fma chain: acc = x*xj; fma(y,..); fma(z,..)
    float dot = fmaf(pz, z, fmaf(py, y, __fmul_rn(px, x)));
    float d2 = __fadd_rn(__fsub_rn(sqi, __fmul_rn(2.0f, dot)), sqj);
    key[s] = (j == i) ? 0xFFFFFFFFu : fmapu(d2);
  }
  if (tid == 0) s_need = KNB;
  u32 prefix = 0u;
#pragma unroll
  for (int r = 0; r < 4; ++r) {
    int shift = 24 - 8*r;
    for (int t = tid; t < 1024; t += 256) ((int*)hist)[t] = 0;
    __syncthreads();
    u32 mask_hi = (r == 0) ? 0u : (0xFFFFFFFFu << (shift + 8));
#pragma unroll
    for (int s = 0; s < 16; ++s) {
      if ((key[s] & mask_hi) == prefix)
        atomicAdd(&hist[wv][(key[s] >> shift) & 255], 1);
    }
    __syncthreads();
    if (tid < 64) {   // exactly wave 0: scan 256 bins, find bin of rank s_need
      int b0 = tid * 4;
      int c0 = hist[0][b0  ]+hist[1][b0  ]+hist[2][b0  ]+hist[3][b0  ];
      int c1 = hist[0][b0+1]+hist[1][b0+1]+hist[2][b0+1]+hist[3][b0+1];
      int c2 = hist[0][b0+2]+hist[1][b0+2]+hist[2][b0+2]+hist[3][b0+2];
      int c3 = hist[0][b0+3]+hist[1][b0+3]+hist[2][b0+3]+hist[3][b0+3];
      int need = s_need;          // wave-lockstep: read before any lane writes
      int tot = c0 + c1 + c2 + c3;
      int x = tot;
#pragma unroll
      for (int o = 1; o < 64; o <<= 1) {
        int v = __shfl_up(x, o, 64);
        if (tid >= o) x += v;
      }
      int cum = x - tot;          // exclusive prefix for this lane's first bin
      if (need > cum && need <= cum + c0) { s_bin = b0;   s_below = cum; }
      cum += c0;
      if (need > cum && need <= cum + c1) { s_bin = b0+1; s_below = cum; }
      cum += c1;
      if (need > cum && need <= cum + c2) { s_bin = b0+2; s_below = cum; }
      cum += c2;
      if (need > cum && need <= cum + c3) { s_bin = b0+3; s_below = cum; }
    }
    __syncthreads();
    prefix |= (u32)s_bin << shift;
    if (tid == 0) s_need = s_need - s_below;
    // next round's post-zero barrier orders s_need for wave 0's next read
  }
  u32 tau = prefix;
  if (tid == 0) { s_cnt[0] = 0u; s_cnt[1] = 0u; }
  __syncthreads();
#pragma unroll
  for (int s = 0; s < 16; ++s) {
    int j = s*256 + tid;
    if (key[s] < tau) {
      u32 p = atomicAdd(&s_cnt[0], 1u);
      knn_idx[i*KNB + p] = j;
    } else if (key[s] == tau) {
      u32 p = atomicAdd(&s_cnt[1], 1u);
      if (p < 256u) s_eq[p] = j;
    }
  }
  __syncthreads();
  if (tid == 0) {
    int cls = (int)s_cnt[0];
    int ceq = (int)s_cnt[1]; if (ceq > 256) ceq = 256;
    int need = KNB - cls;
    for (int r = 0; r < need; ++r) {      // smallest indices among ties
      int best = 1 << 30, bidx = 0;
      for (int t = 0; t < ceq; ++t) {
        int v = s_eq[t];
        if (v < best) { best = v; bidx = t; }
      }
      s_eq[bidx] = 1 << 30;
      knn_idx[i*KNB + cls + r] = best;
    }
  }
}

// ---------- mark unique edges in row bitmap ----------
__global__ void bitmap_kernel(const int* __restrict__ ei, const int* __restrict__ knn_idx,
                              u64* __restrict__ bR) {
  int m = blockIdx.x * 256 + threadIdx.x;
  if (m >= NM) return;
  int s, d; edge_decode(m, ei, knn_idx, s, d);
  atomicOr(&bR[(size_t)s*W64 + (d >> 6)], 1ull << (d & 63));
}

// ---------- fused: bitmap-row decode (deg + ELL cols) -> theta max -> ------
// dev = relu(W_phi .) -> q,k.  8 waves/block, wave = node.
__global__ __launch_bounds__(512) void theta_devqk_kernel(const float* __restrict__ pts,
    const u64* __restrict__ bR, int* __restrict__ deg, uint2* __restrict__ cvT,
    const float* __restrict__ Wt, const float* __restrict__ bt,
    const float* __restrict__ Wp, const float* __restrict__ bp,
    const float* __restrict__ Wq, const float* __restrict__ bq,
    const float* __restrict__ Wk, const float* __restrict__ bk,
    float* __restrict__ qv, float* __restrict__ kv) {
  __shared__ float Wps[HD*TDP], Wqs[HD*TDP], Wks[HD*TDP];  // 3 x 16.25KB
  __shared__ float mf[8][HD];
  __shared__ float dv[8][HD];
  __shared__ int colbuf[8][MAXH];                          // 3KB
  int tid = threadIdx.x;
  for (int m = tid; m < HD*HD; m += 512) {
    int row = m >> 6, col = m & 63;
    Wps[row*TDP + col] = Wp[m];
    Wqs[row*TDP + col] = Wq[m];
    Wks[row*TDP + col] = Wk[m];
  }
  int lane = tid & 63, sub = tid >> 6;
  int i = blockIdx.x * 8 + sub;
  // --- decode bitmap row i: lane = word index (coalesced) ---
  u64 word = bR[(size_t)i*W64 + lane];
  int cnt = __popcll(word);
  int x = cnt;
#pragma unroll
  for (int o = 1; o < 64; o <<= 1) {
    int v = __shfl_up(x, o, 64);
    if (lane >= o) x += v;
  }
  int rank = x - cnt;                 // exclusive prefix
  int degi = __shfl(x, 63, 64);       // total set bits
  if (lane == 63) deg[i] = x;
  int ci = i >> 6, il = i & 63;
  u32* colTx = (u32*)cvT;             // .x components at even u32 offsets
  int slot = rank;
  u64 wtmp = word;
  while (wtmp) {
    int b = __builtin_ctzll(wtmp); wtmp &= wtmp - 1;
    int col = lane*64 + b;
    colbuf[sub][slot] = col;
    colTx[(((size_t)(ci*MAXH + slot) << 6) + il) << 1] = (u32)col;
    ++slot;
  }
  __syncthreads();
  // --- theta max over neighbors (cols ascending, same order as before) ---
  float w0 = Wt[lane*3+0], w1 = Wt[lane*3+1], w2 = Wt[lane*3+2], bb = bt[lane];
  float px = pts[i*3+0], py = pts[i*3+1], pz = pts[i*3+2];
  float m = -INFINITY;
  for (int e = 0; e < degi; ++e) {
    int d = colbuf[sub][e];
    float dx = __fsub_rn(pts[d*3+0], px);
    float dy = __fsub_rn(pts[d*3+1], py);
    float dz = __fsub_rn(pts[d*3+2], pz);
    float t = fmaf(dz, w2, fmaf(dy, w1, __fmul_rn(dx, w0)));
    m = fmaxf(m, __fadd_rn(t, bb));
  }
  mf[sub][lane] = m;
  __syncthreads();
  float a = 0.f;
#pragma unroll
  for (int t = 0; t < HD; ++t) a = fmaf(Wps[lane*TDP + t], mf[sub][t], a);
  float dvv = a + bp[lane];
  dv[sub][lane] = dvv > 0.f ? dvv : 0.f;
  __syncthreads();
  float aq = 0.f, ak = 0.f;
#pragma unroll
  for (int t = 0; t < HD; ++t) {
    float xv = dv[sub][t];
    aq = fmaf(Wqs[lane*TDP + t], xv, aq);
    ak = fmaf(Wks[lane*TDP + t], xv, ak);
  }
  qv[(size_t)i*HD + lane] = aq + bq[lane];
  kv[(size_t)i*HD + lane] = ak + bk[lane];
}

// ---------- fused denom (raw edges) + UNNORMALIZED vals (ELL slots) --------
// Softmax division deferred to final_kernel: A_s[i,j] =
//   (sum_l e~_jl * T~[i,l]) / (denom_i * denom_j).
#define DENOM_BLKS ((NM + 255) / 256)
#define ELL_BLKS   (NCH * MAXH * 64 / 256)
__global__ void vals_kernel(const int* __restrict__ ei, const int* __restrict__ knn_idx,
    const int* __restrict__ deg,
    const float* __restrict__ qv, const float* __restrict__ kv,
    float* __restrict__ denom, uint2* __restrict__ cvT) {
  if ((int)blockIdx.x < DENOM_BLKS) {
    // denom over ALL M raw edges (duplicates count)
    int m = blockIdx.x * 256 + threadIdx.x;
    if (m >= NM) return;
    int s, d; edge_decode(m, ei, knn_idx, s, d);
    float e = expf(dot64(qv + (size_t)d*HD, kv + (size_t)s*HD));
    atomicAdd(&denom[s], e);
  } else {
    // unnormalized e~ per ELL slot: t = (c*MAXH + s)*64 + jl
    int t = (blockIdx.x - DENOM_BLKS) * 256 + threadIdx.x;
    int c = t / (MAXH * 64);
    int r = t - c * (MAXH * 64);
    int s = r >> 6, jl = r & 63;
    int j = c * 64 + jl;
    if (s >= deg[j]) return;
    u32 l = ((const u32*)cvT)[(size_t)t << 1];
    float sc = dot64(qv + (size_t)l*HD, kv + (size_t)j*HD);
    ((u32*)cvT)[((size_t)t << 1) + 1] = __float_as_uint(expf(sc));
  }
}

// ---------- A_s rows [i0,i0+4): Phase A scatter into packed float4 LDS, ----
// Phase B coalesced ELL gather, 4-deep batches, divide by denoms at store.
__global__ __launch_bounds__(1024, 8) void final_kernel(
    const int* __restrict__ deg, const uint2* __restrict__ cvT,
    const float* __restrict__ denom, float* __restrict__ out) {
  __shared__ float4 T4[NN];   // 64KB packed T~[l][0..3]
  int tid = threadIdx.x;
  int i0 = blockIdx.x * RB;
  float4 z4 = make_float4(0.f, 0.f, 0.f, 0.f);
  for (int t = tid; t < NN; t += 1024) T4[t] = z4;
  __syncthreads();
  int w = tid >> 6, lane = tid & 63;
  float* Tf = (float*)T4;
  const u32* colTx = (const u32*)cvT;
  // Phase A: 4 waves per output row r; T~_r[l] += e~[i0+r,k] for l in out(k)
  {
    int r = w & (RB - 1);
    int i = i0 + r;
    int ci = i >> 6, il = i & 63;
    int degi = deg[i];
    for (int idx = (w >> 2); idx < degi; idx += RB) {
      uint2 e = cvT[((size_t)(ci*MAXH + idx) << 6) + il];   // uniform
      int k = (int)e.x; float wv = __uint_as_float(e.y);
      int ck = k >> 6, kl = k & 63;
      int degk = deg[k];
      for (int t = lane; t < degk; t += 64) {
        u32 l = colTx[(((size_t)(ck*MAXH + t) << 6) + kl) << 1];
        atomicAdd(&Tf[(int)l * 4 + r], wv);
      }
    }
  }
  __syncthreads();
  // Phase B: thread owns cols {tid + g*1024}; 4-deep batches give 4
  // independent load->ds_read->fma chains in flight.
  float acc[4][RB];
#pragma unroll
  for (int g = 0; g < 4; ++g)
#pragma unroll
    for (int r = 0; r < RB; ++r) acc[g][r] = 0.f;
#pragma unroll
  for (int g = 0; g < 4; ++g) {
    int j = tid + g * 1024;
    int c = j >> 6;                 // wave-uniform chunk
    int dj = deg[j];
    const uint2* p = cvT + ((size_t)(c*MAXH) << 6) + (j & 63);
    int s = 0;
    for (; s + 4 <= dj; s += 4) {
      uint2 e0 = p[(size_t)(s+0) << 6];
      uint2 e1 = p[(size_t)(s+1) << 6];
      uint2 e2 = p[(size_t)(s+2) << 6];
      uint2 e3 = p[(size_t)(s+3) << 6];
      float4 t0 = T4[(int)e0.x];
      float4 t1 = T4[(int)e1.x];
      float4 t2 = T4[(int)e2.x];
      float4 t3 = T4[(int)e3.x];
      float v0 = __uint_as_float(e0.y), v1 = __uint_as_float(e1.y);
      float v2 = __uint_as_float(e2.y), v3 = __uint_as_float(e3.y);
      acc[g][0] = fmaf(v0, t0.x, acc[g][0]); acc[g][1] = fmaf(v0, t0.y, acc[g][1]);
      acc[g][2] = fmaf(v0, t0.z, acc[g][2]); acc[g][3] = fmaf(v0, t0.w, acc[g][3]);
      acc[g][0] = fmaf(v1, t1.x, acc[g][0]); acc[g][1] = fmaf(v1, t1.y, acc[g][1]);
      acc[g][2] = fmaf(v1, t1.z, acc[g][2]); acc[g][3] = fmaf(v1, t1.w, acc[g][3]);
      acc[g][0] = fmaf(v2, t2.x, acc[g][0]); acc[g][1] = fmaf(v2, t2.y, acc[g][1]);
      acc[g][2] = fmaf(v2, t2.z, acc[g][2]); acc[g][3] = fmaf(v2, t2.w, acc[g][3]);
      acc[g][0] = fmaf(v3, t3.x, acc[g][0]); acc[g][1] = fmaf(v3, t3.y, acc[g][1]);
      acc[g][2] = fmaf(v3, t3.z, acc[g][2]); acc[g][3] = fmaf(v3, t3.w, acc[g][3]);
    }
    for (; s < dj; ++s) {
      uint2 e = p[(size_t)s << 6];
      float v = __uint_as_float(e.y);
      float4 tv = T4[(int)e.x];
      acc[g][0] = fmaf(v, tv.x, acc[g][0]);
      acc[g][1] = fmaf(v, tv.y, acc[g][1]);
      acc[g][2] = fmaf(v, tv.z, acc[g][2]);
      acc[g][3] = fmaf(v, tv.w, acc[g][3]);
    }
  }
  float rden[RB];
#pragma unroll
  for (int r = 0; r < RB; ++r) rden[r] = 1.0f / denom[i0 + r];
#pragma unroll
  for (int g = 0; g < 4; ++g) {
    int j = tid + g * 1024;
    float dj_den = denom[j];
#pragma unroll
    for (int r = 0; r < RB; ++r)
      out[(size_t)(i0 + r) * NN + j] = acc[g][r] * rden[r] / dj_den;
  }
}

extern "C" void kernel_launch(void* const* d_in, const int* in_sizes, int n_in,
                              void* d_out, int out_size, void* d_ws, size_t ws_size,
                              hipStream_t stream) {
  (void)in_sizes; (void)n_in; (void)out_size;
  const float* pts = (const float*)d_in[0];
  // d_in[1] = features: unused by the reference
  const int* ei = (const int*)d_in[2];
  const float* Wt = (const float*)d_in[3];
  const float* bt = (const float*)d_in[4];
  const float* Wp = (const float*)d_in[5];
  const float* bp = (const float*)d_in[6];
  const float* Wq = (const float*)d_in[7];
  const float* bq = (const float*)d_in[8];
  const float* Wk = (const float*)d_in[9];
  const float* bk = (const float*)d_in[10];
  float* out = (float*)d_out;

  char* w = (char*)d_ws;
  // zeroed region first (contiguous): bR, denom
  u64* bR = (u64*)w;        w += (size_t)NN*W64*8;       // 2MB
  float* denom = (float*)w; w += (size_t)NN*4;           // 16KB
  float* qv = (float*)w;    w += (size_t)NN*HD*4;        // 1MB
  float* kv = (float*)w;    w += (size_t)NN*HD*4;        // 1MB
  int* knn_idx = (int*)w;   w += (size_t)NN*KNB*4;
  int* deg = (int*)w;       w += (size_t)NN*4;
  uint2* cvT = (uint2*)w;   w += (size_t)NCH*MAXH*64*8;  // 3MB (padding never read)
  if ((size_t)(w - (char*)d_ws) > ws_size) return;  // insufficient scratch

  int zero_u32s = (int)(((size_t)NN*W64*8 + (size_t)NN*4) / 4);
  hipLaunchKernelGGL(knn_kernel, dim3(NN), dim3(256), 0, stream,
                     pts, knn_idx, (u32*)d_ws, zero_u32s);
  hipLaunchKernelGGL(bitmap_kernel, dim3((NM+255)/256), dim3(256), 0, stream,
                     ei, knn_idx, bR);
  hipLaunchKernelGGL(theta_devqk_kernel, dim3(NN/8), dim3(512), 0, stream,
                     pts, bR, deg, cvT, Wt, bt, Wp, bp, Wq, bq, Wk, bk, qv, kv);
  hipLaunchKernelGGL(vals_kernel, dim3(DENOM_BLKS + ELL_BLKS), dim3(256), 0, stream,
                     ei, knn_idx, deg, qv, kv, denom, cvT);
  hipLaunchKernelGGL(final_kernel, dim3(NN/RB), dim3(1024), 0, stream,
                     deg, cvT, denom, out);
}

// Round 10
// 177.713 us; speedup vs baseline: 2.9628x; 1.0378x over previous
//
#include <hip/hip_runtime.h>

#define NN 4096
#define HD 64
#define KNB 15
#define NE 32768
#define NM (NE + NN*KNB)   // 94208 edges total (with duplicates)
#define W64 (NN/64)        // 64 u64 words per bitmap row
#define RB 4               // output rows per block in final_kernel
#define MAXH 96            // ELL pitch: max slices per 64-col chunk
#define NCH (NN/64)        // 64 column chunks
#define TDP 65             // padded LDS stride for 64x64 weights (conflict-free)

typedef unsigned long long u64;
typedef unsigned int u32;

// order-preserving float->uint map
__device__ __forceinline__ u32 fmapu(float f) {
  int i = __float_as_int(f);
  return (u32)(i ^ ((i >> 31) | 0x80000000));
}

__device__ __forceinline__ u64 shfl_xor_u64(u64 v, int off) {
  int lo = __shfl_xor((int)(v & 0xFFFFFFFFull), off, 64);
  int hi = __shfl_xor((int)(v >> 32), off, 64);
  return ((u64)(u32)hi << 32) | (u32)lo;
}

__device__ __forceinline__ float dot64(const float* __restrict__ a,
                                       const float* __restrict__ b) {
  const float4* a4 = (const float4*)a;
  const float4* b4 = (const float4*)b;
  float s = 0.f;
#pragma unroll
  for (int t = 0; t < 16; ++t) {
    float4 x = a4[t], y = b4[t];
    s = fmaf(x.x, y.x, s); s = fmaf(x.y, y.y, s);
    s = fmaf(x.z, y.z, s); s = fmaf(x.w, y.w, s);
  }
  return s;
}

__device__ __forceinline__ void edge_decode(int m, const int* __restrict__ ei,
                                            const int* __restrict__ knn_idx,
                                            int& s, int& d) {
  if (m < NE) { s = ei[m]; d = ei[NE + m]; }
  else { int mm = m - NE; s = mm / KNB; d = knn_idx[mm]; }
}

// ---------- KNN: block per node; iterative top-15 extraction ---------------
// Each thread holds 16 candidates as u64 (key<<32 | j); 15 rounds of
// block-min extract the 15 lexicographically smallest (d2, j) pairs.
// The block also writes its own bR row (plain stores -- block i owns row i)
// and zeroes denom via a folded fill.
__global__ __launch_bounds__(256) void knn_kernel(const float* __restrict__ pts,
                                                  int* __restrict__ knn_idx,
                                                  u64* __restrict__ bR,
                                                  u32* __restrict__ zero_base,
                                                  int zero_n) {
  // fold: zero denom (contiguous); one u32 per thread, blocks 0..15 active
  int zi = blockIdx.x * 256 + threadIdx.x;
  if (zi < zero_n) zero_base[zi] = 0u;

  __shared__ u64 sm[KNB][4];     // per-round wave minima
  __shared__ u64 s_mask[64];     // own bitmap row
  __shared__ int s_j[KNB];       // selected neighbor ids
  int i = blockIdx.x;
  int tid = threadIdx.x;
  int lane = tid & 63, wv = tid >> 6;
  float px = pts[i*3+0], py = pts[i*3+1], pz = pts[i*3+2];
  // match np: (x*x + y*y) + z*z, no fma contraction
  float sqi = __fadd_rn(__fadd_rn(__fmul_rn(px,px), __fmul_rn(py,py)), __fmul_rn(pz,pz));
  u64 lk[16];
#pragma unroll
  for (int s = 0; s < 16; ++s) {
    int j = s*256 + tid;
    float x = pts[j*3+0], y = pts[j*3+1], z = pts[j*3+2];
    float sqj = __fadd_rn(__fadd_rn(__fmul_rn(x,x), __fmul_rn(y,y)), __fmul_rn(z,z));
    // match BLAS fma chain: acc = x*xj; fma(y,..); fma(z,..)
    float dot = fmaf(pz, z, fmaf(py, y, __fmul_rn(px, x)));
    float d2 = __fadd_rn(__fsub_rn(sqi, __fmul_rn(2.0f, dot)), sqj);
    u32 key = (j == i) ? 0xFFFFFFFFu : fmapu(d2);   // finite d2 keys < 0xFFFFFFFF
    lk[s] = ((u64)key << 32) | (u32)j;
  }
  // local min of 16 (registers, static indices)
  u64 lmin = lk[0];
#pragma unroll
  for (int s = 1; s < 16; ++s) lmin = (lk[s] < lmin) ? lk[s] : lmin;

  for (int r = 0; r < KNB; ++r) {
    u64 v = lmin;
#pragma unroll
    for (int off = 32; off >= 1; off >>= 1) {
      u64 o = shfl_xor_u64(v, off);
      if (o < v) v = o;
    }
    if (lane == 0) sm[r][wv] = v;
    __syncthreads();
    u64 bm = sm[r][0];
    if (sm[r][1] < bm) bm = sm[r][1];
    if (sm[r][2] < bm) bm = sm[r][2];
    if (sm[r][3] < bm) bm = sm[r][3];
    int j = (int)(u32)(bm & 0xFFFFFFFFull);
    if (tid == 0) { knn_idx[i*KNB + r] = j; s_j[r] = j; }
    int owner = j & 255, sid = j >> 8;
    if (tid == owner) {
#pragma unroll
      for (int s2 = 0; s2 < 16; ++s2) if (s2 == sid) lk[s2] = ~0ull;
    }
    lmin = lk[0];
#pragma unroll
    for (int s2 = 1; s2 < 16; ++s2) lmin = (lk[s2] < lmin) ? lk[s2] : lmin;
  }
  // own bR row: mask of the 15 selected neighbors (plain stores; ei bits
  // are OR'd in by bitmap_kernel afterwards)
  if (tid < 64) s_mask[tid] = 0ull;
  __syncthreads();
  if (tid < KNB) {
    int j = s_j[tid];
    atomicOr(&s_mask[j >> 6], 1ull << (j & 63));
  }
  __syncthreads();
  if (tid < 64) bR[(size_t)i*W64 + tid] = s_mask[tid];
}

// ---------- OR the explicit ei edges into the row bitmap ----------
__global__ void bitmap_kernel(const int* __restrict__ ei, u64* __restrict__ bR) {
  int m = blockIdx.x * 256 + threadIdx.x;
  if (m >= NE) return;
  int s = ei[m], d = ei[NE + m];
  atomicOr(&bR[(size_t)s*W64 + (d >> 6)], 1ull << (d & 63));
}

// ---------- fused: bitmap-row decode (deg + ELL cols) -> theta max -> ------
// dev = relu(W_phi .) -> q,k.  8 waves/block, wave = node.
__global__ __launch_bounds__(512) void theta_devqk_kernel(const float* __restrict__ pts,
    const u64* __restrict__ bR, int* __restrict__ deg, uint2* __restrict__ cvT,
    const float* __restrict__ Wt, const float* __restrict__ bt,
    const float* __restrict__ Wp, const float* __restrict__ bp,
    const float* __restrict__ Wq, const float* __restrict__ bq,
    const float* __restrict__ Wk, const float* __restrict__ bk,
    float* __restrict__ qv, float* __restrict__ kv) {
  __shared__ float Wps[HD*TDP], Wqs[HD*TDP], Wks[HD*TDP];  // 3 x 16.25KB
  __shared__ float mf[8][HD];
  __shared__ float dv[8][HD];
  __shared__ int colbuf[8][MAXH];                          // 3KB
  int tid = threadIdx.x;
  for (int m = tid; m < HD*HD; m += 512) {
    int row = m >> 6, col = m & 63;
    Wps[row*TDP + col] = Wp[m];
    Wqs[row*TDP + col] = Wq[m];
    Wks[row*TDP + col] = Wk[m];
  }
  int lane = tid & 63, sub = tid >> 6;
  int i = blockIdx.x * 8 + sub;
  // --- decode bitmap row i: lane = word index (coalesced) ---
  u64 word = bR[(size_t)i*W64 + lane];
  int cnt = __popcll(word);
  int x = cnt;
#pragma unroll
  for (int o = 1; o < 64; o <<= 1) {
    int v = __shfl_up(x, o, 64);
    if (lane >= o) x += v;
  }
  int rank = x - cnt;                 // exclusive prefix
  int degi = __shfl(x, 63, 64);       // total set bits
  if (lane == 63) deg[i] = x;
  int ci = i >> 6, il = i & 63;
  u32* colTx = (u32*)cvT;             // .x components at even u32 offsets
  int slot = rank;
  u64 wtmp = word;
  while (wtmp) {
    int b = __builtin_ctzll(wtmp); wtmp &= wtmp - 1;
    int col = lane*64 + b;
    colbuf[sub][slot] = col;
    colTx[(((size_t)(ci*MAXH + slot) << 6) + il) << 1] = (u32)col;
    ++slot;
  }
  __syncthreads();
  // --- theta max over neighbors (cols ascending, same order as before) ---
  float w0 = Wt[lane*3+0], w1 = Wt[lane*3+1], w2 = Wt[lane*3+2], bb = bt[lane];
  float px = pts[i*3+0], py = pts[i*3+1], pz = pts[i*3+2];
  float m = -INFINITY;
  for (int e = 0; e < degi; ++e) {
    int d = colbuf[sub][e];
    float dx = __fsub_rn(pts[d*3+0], px);
    float dy = __fsub_rn(pts[d*3+1], py);
    float dz = __fsub_rn(pts[d*3+2], pz);
    float t = fmaf(dz, w2, fmaf(dy, w1, __fmul_rn(dx, w0)));
    m = fmaxf(m, __fadd_rn(t, bb));
  }
  mf[sub][lane] = m;
  __syncthreads();
  float a = 0.f;
#pragma unroll
  for (int t = 0; t < HD; ++t) a = fmaf(Wps[lane*TDP + t], mf[sub][t], a);
  float dvv = a + bp[lane];
  dv[sub][lane] = dvv > 0.f ? dvv : 0.f;
  __syncthreads();
  float aq = 0.f, ak = 0.f;
#pragma unroll
  for (int t = 0; t < HD; ++t) {
    float xv = dv[sub][t];
    aq = fmaf(Wqs[lane*TDP + t], xv, aq);
    ak = fmaf(Wks[lane*TDP + t], xv, ak);
  }
  qv[(size_t)i*HD + lane] = aq + bq[lane];
  kv[(size_t)i*HD + lane] = ak + bk[lane];
}

// ---------- fused denom (raw edges) + UNNORMALIZED vals (ELL slots) --------
// Softmax division deferred to final_kernel: A_s[i,j] =
//   (sum_l e~_jl * T~[i,l]) / (denom_i * denom_j).
#define DENOM_BLKS ((NM + 255) / 256)
#define ELL_BLKS   (NCH * MAXH * 64 / 256)
__global__ void vals_kernel(const int* __restrict__ ei, const int* __restrict__ knn_idx,
    const int* __restrict__ deg,
    const float* __restrict__ qv, const float* __restrict__ kv,
    float* __restrict__ denom, uint2* __restrict__ cvT) {
  if ((int)blockIdx.x < DENOM_BLKS) {
    // denom over ALL M raw edges (duplicates count)
    int m = blockIdx.x * 256 + threadIdx.x;
    if (m >= NM) return;
    int s, d; edge_decode(m, ei, knn_idx, s, d);
    float e = expf(dot64(qv + (size_t)d*HD, kv + (size_t)s*HD));
    atomicAdd(&denom[s], e);
  } else {
    // unnormalized e~ per ELL slot: t = (c*MAXH + s)*64 + jl
    int t = (blockIdx.x - DENOM_BLKS) * 256 + threadIdx.x;
    int c = t / (MAXH * 64);
    int r = t - c * (MAXH * 64);
    int s = r >> 6, jl = r & 63;
    int j = c * 64 + jl;
    if (s >= deg[j]) return;
    u32 l = ((const u32*)cvT)[(size_t)t << 1];
    float sc = dot64(qv + (size_t)l*HD, kv + (size_t)j*HD);
    ((u32*)cvT)[((size_t)t << 1) + 1] = __float_as_uint(expf(sc));
  }
}

// ---------- A_s rows [i0,i0+4): Phase A scatter into packed float4 LDS, ----
// Phase B coalesced ELL gather, 4-deep batches, divide by denoms at store.
__global__ __launch_bounds__(1024, 8) void final_kernel(
    const int* __restrict__ deg, const uint2* __restrict__ cvT,
    const float* __restrict__ denom, float* __restrict__ out) {
  __shared__ float4 T4[NN];   // 64KB packed T~[l][0..3]
  int tid = threadIdx.x;
  int i0 = blockIdx.x * RB;
  float4 z4 = make_float4(0.f, 0.f, 0.f, 0.f);
  for (int t = tid; t < NN; t += 1024) T4[t] = z4;
  __syncthreads();
  int w = tid >> 6, lane = tid & 63;
  float* Tf = (float*)T4;
  const u32* colTx = (const u32*)cvT;
  // Phase A: 4 waves per output row r; T~_r[l] += e~[i0+r,k] for l in out(k)
  {
    int r = w & (RB - 1);
    int i = i0 + r;
    int ci = i >> 6, il = i & 63;
    int degi = deg[i];
    for (int idx = (w >> 2); idx < degi; idx += RB) {
      uint2 e = cvT[((size_t)(ci*MAXH + idx) << 6) + il];   // uniform
      int k = (int)e.x; float wv = __uint_as_float(e.y);
      int ck = k >> 6, kl = k & 63;
      int degk = deg[k];
      for (int t = lane; t < degk; t += 64) {
        u32 l = colTx[(((size_t)(ck*MAXH + t) << 6) + kl) << 1];
        atomicAdd(&Tf[(int)l * 4 + r], wv);
      }
    }
  }
  __syncthreads();
  // Phase B: thread owns cols {tid + g*1024}; 4-deep batches give 4
  // independent load->ds_read->fma chains in flight.
  float acc[4][RB];
#pragma unroll
  for (int g = 0; g < 4; ++g)
#pragma unroll
    for (int r = 0; r < RB; ++r) acc[g][r] = 0.f;
#pragma unroll
  for (int g = 0; g < 4; ++g) {
    int j = tid + g * 1024;
    int c = j >> 6;                 // wave-uniform chunk
    int dj = deg[j];
    const uint2* p = cvT + ((size_t)(c*MAXH) << 6) + (j & 63);
    int s = 0;
    for (; s + 4 <= dj; s += 4) {
      uint2 e0 = p[(size_t)(s+0) << 6];
      uint2 e1 = p[(size_t)(s+1) << 6];
      uint2 e2 = p[(size_t)(s+2) << 6];
      uint2 e3 = p[(size_t)(s+3) << 6];
      float4 t0 = T4[(int)e0.x];
      float4 t1 = T4[(int)e1.x];
      float4 t2 = T4[(int)e2.x];
      float4 t3 = T4[(int)e3.x];
      float v0 = __uint_as_float(e0.y), v1 = __uint_as_float(e1.y);
      float v2 = __uint_as_float(e2.y), v3 = __uint_as_float(e3.y);
      acc[g][0] = fmaf(v0, t0.x, acc[g][0]); acc[g][1] = fmaf(v0, t0.y, acc[g][1]);
      acc[g][2] = fmaf(v0, t0.z, acc[g][2]); acc[g][3] = fmaf(v0, t0.w, acc[g][3]);
      acc[g][0] = fmaf(v1, t1.x, acc[g][0]); acc[g][1] = fmaf(v1, t1.y, acc[g][1]);
      acc[g][2] = fmaf(v1, t1.z, acc[g][2]); acc[g][3] = fmaf(v1, t1.w, acc[g][3]);
      acc[g][0] = fmaf(v2, t2.x, acc[g][0]); acc[g][1] = fmaf(v2, t2.y, acc[g][1]);
      acc[g][2] = fmaf(v2, t2.z, acc[g][2]); acc[g][3] = fmaf(v2, t2.w, acc[g][3]);
      acc[g][0] = fmaf(v3, t3.x, acc[g][0]); acc[g][1] = fmaf(v3, t3.y, acc[g][1]);
      acc[g][2] = fmaf(v3, t3.z, acc[g][2]); acc[g][3] = fmaf(v3, t3.w, acc[g][3]);
    }
    for (; s < dj; ++s) {
      uint2 e = p[(size_t)s << 6];
      float v = __uint_as_float(e.y);
      float4 tv = T4[(int)e.x];
      acc[g][0] = fmaf(v, tv.x, acc[g][0]);
      acc[g][1] = fmaf(v, tv.y, acc[g][1]);
      acc[g][2] = fmaf(v, tv.z, acc[g][2]);
      acc[g][3] = fmaf(v, tv.w, acc[g][3]);
    }
  }
  float rden[RB];
#pragma unroll
  for (int r = 0; r < RB; ++r) rden[r] = 1.0f / denom[i0 + r];
#pragma unroll
  for (int g = 0; g < 4; ++g) {
    int j = tid + g * 1024;
    float dj_den = denom[j];
#pragma unroll
    for (int r = 0; r < RB; ++r)
      out[(size_t)(i0 + r) * NN + j] = acc[g][r] * rden[r] / dj_den;
  }
}

extern "C" void kernel_launch(void* const* d_in, const int* in_sizes, int n_in,
                              void* d_out, int out_size, void* d_ws, size_t ws_size,
                              hipStream_t stream) {
  (void)in_sizes; (void)n_in; (void)out_size;
  const float* pts = (const float*)d_in[0];
  // d_in[1] = features: unused by the reference
  const int* ei = (const int*)d_in[2];
  const float* Wt = (const float*)d_in[3];
  const float* bt = (const float*)d_in[4];
  const float* Wp = (const float*)d_in[5];
  const float* bp = (const float*)d_in[6];
  const float* Wq = (const float*)d_in[7];
  const float* bq = (const float*)d_in[8];
  const float* Wk = (const float*)d_in[9];
  const float* bk = (const float*)d_in[10];
  float* out = (float*)d_out;

  char* w = (char*)d_ws;
  u64* bR = (u64*)w;        w += (size_t)NN*W64*8;       // 2MB (written by knn)
  float* denom = (float*)w; w += (size_t)NN*4;           // 16KB (zeroed via fold)
  float* qv = (float*)w;    w += (size_t)NN*HD*4;        // 1MB
  float* kv = (float*)w;    w += (size_t)NN*HD*4;        // 1MB
  int* knn_idx = (int*)w;   w += (size_t)NN*KNB*4;
  int* deg = (int*)w;       w += (size_t)NN*4;
  uint2* cvT = (uint2*)w;   w += (size_t)NCH*MAXH*64*8;  // 3MB (padding never read)
  if ((size_t)(w - (char*)d_ws) > ws_size) return;  // insufficient scratch

  hipLaunchKernelGGL(knn_kernel, dim3(NN), dim3(256), 0, stream,
                     pts, knn_idx, bR, (u32*)denom, NN);
  hipLaunchKernelGGL(bitmap_kernel, dim3((NE+255)/256), dim3(256), 0, stream,
                     ei, bR);
  hipLaunchKernelGGL(theta_devqk_kernel, dim3(NN/8), dim3(512), 0, stream,
                     pts, bR, deg, cvT, Wt, bt, Wp, bp, Wq, bq, Wk, bk, qv, kv);
  hipLaunchKernelGGL(vals_kernel, dim3(DENOM_BLKS + ELL_BLKS), dim3(256), 0, stream,
                     ei, knn_idx, deg, qv, kv, denom, cvT);
  hipLaunchKernelGGL(final_kernel, dim3(NN/RB), dim3(1024), 0, stream,
                     deg, cvT, denom, out);
}